// Round 12
// baseline (308.363 us; speedup 1.0000x reference)
//
#include <hip/hip_runtime.h>
#include <stdint.h>

typedef __attribute__((ext_vector_type(8))) short bf16x8;
typedef __attribute__((ext_vector_type(4))) float f32x4;
typedef __attribute__((ext_vector_type(4))) unsigned int u32x4;
typedef __attribute__((ext_vector_type(4))) unsigned short u16x4;

#define DEVINL static __device__ __forceinline__

DEVINL unsigned short f2bf(float f) {
  uint32_t u = __builtin_bit_cast(uint32_t, f);
  u = (u + 0x7FFFu + ((u >> 16) & 1u)) >> 16;
  return (unsigned short)u;
}

DEVINL float fexp2(float x) {
#if __has_builtin(__builtin_amdgcn_exp2f)
  return __builtin_amdgcn_exp2f(x);
#else
  return __expf(x * 0.69314718056f);
#endif
}

// raw barrier: order LDS (lgkmcnt) but leave global nt stores / reg-loads in flight
DEVINL void barrier_lds_only() {
  asm volatile("s_waitcnt lgkmcnt(0)" ::: "memory");
  __builtin_amdgcn_sched_barrier(0);
  __builtin_amdgcn_s_barrier();
  __builtin_amdgcn_sched_barrier(0);
}

// pack 8 fp32 -> 8 bf16 (RNE) via v_cvt_pk_bf16_f32 (register-only asm)
DEVINL bf16x8 pack8(f32x4 a, f32x4 b) {
  union { uint32_t u[4]; bf16x8 v; } r;
  asm("v_cvt_pk_bf16_f32 %0, %1, %2" : "=v"(r.u[0]) : "v"(a[0]), "v"(a[1]));
  asm("v_cvt_pk_bf16_f32 %0, %1, %2" : "=v"(r.u[1]) : "v"(a[2]), "v"(a[3]));
  asm("v_cvt_pk_bf16_f32 %0, %1, %2" : "=v"(r.u[2]) : "v"(b[0]), "v"(b[1]));
  asm("v_cvt_pk_bf16_f32 %0, %1, %2" : "=v"(r.u[3]) : "v"(b[2]), "v"(b[3]));
  return r.v;
}

// async global->LDS, 16B per lane; lds base must be wave-uniform (lane*16 implicit)
DEVINL void async16(unsigned short* lds, const unsigned short* g) {
  __builtin_amdgcn_global_load_lds(
      (const __attribute__((address_space(1))) unsigned int*)g,
      (__attribute__((address_space(3))) unsigned int*)lds, 16, 0, 0);
}

// ---------------- cast x (fp32 -> bf16), vectorized ----------------
__global__ __launch_bounds__(256) void k_cast_x(const float* __restrict__ in,
                                                unsigned short* __restrict__ out, int n4) {
  int i = blockIdx.x * 256 + threadIdx.x;
  if (i >= n4) return;
  f32x4 v = *(const f32x4*)(in + (size_t)i * 4);
  u16x4 o;
  for (int j = 0; j < 4; ++j) o[j] = f2bf(v[j]);
  *(u16x4*)(out + (size_t)i * 4) = o;
}

// ------------- transpose-cast W: in [K][N] f32 -> out [N][K] bf16 -------------
__global__ __launch_bounds__(256) void k_transpose_w(const float* __restrict__ in,
                                                     unsigned short* __restrict__ out,
                                                     int K, int N) {
  __shared__ unsigned short tile[64][72];
  int k0 = blockIdx.x * 64, n0 = blockIdx.y * 64;
  int t = threadIdx.x;
  int r = t >> 2, c0 = (t & 3) * 16;
  for (int j = 0; j < 4; ++j) {
    int col = c0 + j * 4;
    f32x4 v = *(const f32x4*)(in + (size_t)(k0 + r) * N + n0 + col);
    u16x4 o;
    for (int q = 0; q < 4; ++q) o[q] = f2bf(v[q]);
    *(u16x4*)(&tile[r][col]) = o;
  }
  __syncthreads();
  for (int j = 0; j < 4; ++j) {
    int kcol = c0 + j * 4;
    u16x4 o;
    for (int q = 0; q < 4; ++q) o[q] = tile[kcol + q][r];
    *(u16x4*)(out + (size_t)(n0 + r) * K + k0 + kcol) = o;
  }
}

// ---------------- GEMM: A[M][1024] bf16  x  Bt[N][1024] bf16 ----------------
template <int MODE>
__global__ __launch_bounds__(256) void k_gemm(const unsigned short* __restrict__ A,
                                              const unsigned short* __restrict__ Bt,
                                              const float* __restrict__ bias,
                                              unsigned short* __restrict__ Qb,
                                              unsigned short* __restrict__ Kb,
                                              unsigned short* __restrict__ Vt,
                                              float* __restrict__ outF) {
  constexpr int KD = 1024;
  __shared__ unsigned short sh[17408];
  unsigned short* lA = sh;
  unsigned short* lB = sh + 8192;
  int tid = threadIdx.x;
  int lane = tid & 63, w = tid >> 6;
  int wr = w >> 1, wc = w & 1;
  int m0 = blockIdx.x * 128, n0 = blockIdx.y * 128;
  int lr = lane & 15, lg = lane >> 4;

  f32x4 acc[4][4] = {};

  int srow = w * 32 + (lane >> 3);
  int scol = (lane & 7) * 8;
  const unsigned short* gA = A + (size_t)(m0 + srow) * KD + scol;
  const unsigned short* gB = Bt + (size_t)(n0 + srow) * KD + scol;

  for (int kk = 0; kk < KD; kk += 64) {
    for (int s = 0; s < 4; ++s) {
      async16(&lA[(w * 32 + s * 8) * 64], gA + (size_t)s * 8 * KD + kk);
      async16(&lB[(w * 32 + s * 8) * 64], gB + (size_t)s * 8 * KD + kk);
    }
    __syncthreads();
    for (int kq = 0; kq < 2; ++kq) {
      bf16x8 af[4], bfr[4];
      for (int i = 0; i < 4; ++i)
        af[i] = *(const bf16x8*)(&lA[(wr * 64 + i * 16 + lr) * 64 + (kq * 4 + lg) * 8]);
      for (int r = 0; r < 4; ++r)
        bfr[r] = *(const bf16x8*)(&lB[(wc * 64 + r * 16 + lr) * 64 + (kq * 4 + lg) * 8]);
      for (int i = 0; i < 4; ++i)
        for (int r = 0; r < 4; ++r)
          acc[i][r] = __builtin_amdgcn_mfma_f32_16x16x32_bf16(af[i], bfr[r], acc[i][r], 0, 0, 0);
    }
    __syncthreads();
  }

  if (MODE == 0) {
    int which = n0 >> 10;
    int head0 = (n0 & 1023) >> 6;
    int b_idx = m0 >> 11;
    int l0 = m0 & 2047;
    if (which < 2) {
      for (int r = 0; r < 4; ++r) {
        int nl = wc * 64 + r * 16 + lr;
        float bv = bias[n0 + nl];
        for (int i = 0; i < 4; ++i) {
          int mlb = wr * 64 + i * 16 + lg * 4;
          for (int jj = 0; jj < 4; ++jj)
            sh[(mlb + jj) * 136 + nl] = f2bf(acc[i][r][jj] + bv);
        }
      }
      __syncthreads();
      unsigned short* dst = (which == 0) ? Qb : Kb;
      for (int it = 0; it < 4; ++it) {
        int row = it * 64 + (tid >> 2);
        int ml = row & 127, hd = row >> 7;
        int c = (tid & 3) * 16;
        bf16x8 v0 = *(const bf16x8*)&sh[ml * 136 + hd * 64 + c];
        bf16x8 v1 = *(const bf16x8*)&sh[ml * 136 + hd * 64 + c + 8];
        size_t bh = (size_t)(b_idx * 16 + head0 + hd);
        size_t off = (bh * 2048 + l0 + ml) * 64 + c;
        *(bf16x8*)(dst + off) = v0;
        *(bf16x8*)(dst + off + 8) = v1;
      }
    } else {
      for (int r = 0; r < 4; ++r) {
        int nl = wc * 64 + r * 16 + lr;
        float bv = bias[n0 + nl];
        for (int i = 0; i < 4; ++i) {
          int mlb = wr * 64 + i * 16 + lg * 4;
          u16x4 pk;
          for (int jj = 0; jj < 4; ++jj) pk[jj] = f2bf(acc[i][r][jj] + bv);
          *(u16x4*)&sh[nl * 136 + mlb] = pk;
        }
      }
      __syncthreads();
      for (int it = 0; it < 4; ++it) {
        int nl = it * 32 + (tid >> 3);
        int c = (tid & 7) * 16;
        bf16x8 v0 = *(const bf16x8*)&sh[nl * 136 + c];
        bf16x8 v1 = *(const bf16x8*)&sh[nl * 136 + c + 8];
        int dk = nl & 63, hd = nl >> 6;
        size_t bh = (size_t)(b_idx * 16 + head0 + hd);
        size_t off = (bh * 64 + dk) * 2048 + l0 + c;
        *(bf16x8*)(Vt + off) = v0;
        *(bf16x8*)(Vt + off + 8) = v1;
      }
    }
  } else {
    for (int r = 0; r < 4; ++r) {
      int n = n0 + wc * 64 + r * 16 + lr;
      float bv = bias[n];
      for (int i = 0; i < 4; ++i) {
        int mb = m0 + wr * 64 + i * 16 + lg * 4;
        for (int jj = 0; jj < 4; ++jj)
          outF[(size_t)(mb + jj) * 1024 + n] = acc[i][r][jj] + bv;
      }
    }
  }
}

// ---------------- fused attention (v4: R11 + explicit register pipelining) ----------------
// Same math/order as R11. K fragments double-buffered across groups (issue g+1's
// loads before computing g); V fragments issued at group top, consumed in PV
// ~800 cyc later. Attacks the exposed global-load latency in the dependent chain
// (R5 PMC: MfmaUtil 5.6% == 51.6 GF / 370 us exactly; all pipes idle).
__global__ __launch_bounds__(256) void k_attn(const unsigned short* __restrict__ Qb,
                                              const unsigned short* __restrict__ Kb,
                                              const unsigned short* __restrict__ Vt,
                                              float* __restrict__ attn,
                                              unsigned short* __restrict__ ctx) {
  __shared__ float Pf[32 * 260];
  __shared__ float Ls[4][32];
  __shared__ float Linv[32];
  int tid = threadIdx.x, lane = tid & 63, w = tid >> 6;
  int lr = lane & 15, lg = lane >> 4;
  int bid = blockIdx.x;
  int xcd = bid & 7, slot = bid >> 3;       // slot 0..255
  int bh = xcd * 4 + (slot >> 6);           // 4 heads per XCD
  int rb = slot & 63;
  int q0 = rb * 32;
  int b_idx = bh >> 4, h = bh & 15;
  const unsigned short* Qh = Qb + (size_t)bh * 2048 * 64;
  const unsigned short* Kh = Kb + (size_t)bh * 2048 * 64;
  const unsigned short* Vh = Vt + (size_t)bh * 64 * 2048;
  const float A2 = 0.125f * 1.44269504089f;  // scale * log2(e)

  bf16x8 qf[2][2];
  for (int i = 0; i < 2; ++i)
    for (int kq = 0; kq < 2; ++kq)
      qf[i][kq] = *(const bf16x8*)(Qh + (size_t)(q0 + i * 16 + lr) * 64 + kq * 32 + lg * 8);

  bf16x8 kfA[2][4], kfB[2][4];
  auto load_kf = [&](bf16x8 (&buf)[2][4], int kt) {
    for (int kq = 0; kq < 2; ++kq) {
      int kof = kq * 32 + lg * 8;
      for (int r = 0; r < 4; ++r)
        buf[kq][r] = *(const bf16x8*)(Kh + (size_t)(kt * 64 + r * 16 + lr) * 64 + kof);
    }
  };

  float l_run[8] = {0.f, 0.f, 0.f, 0.f, 0.f, 0.f, 0.f, 0.f};

  // ---- pass 1: wave w sums exp over kts {4g+w}; 2-deep kf pipeline ----
  auto p1body = [&](int g, bf16x8 (&CUR)[2][4], bf16x8 (&NXT)[2][4], bool pre) {
    if (pre) load_kf(NXT, (g + 1) * 4 + w);
    __builtin_amdgcn_sched_barrier(0);   // pin prefetch issue before compute
    f32x4 acc[2][4] = {};
    for (int kq = 0; kq < 2; ++kq)
      for (int i = 0; i < 2; ++i)
        for (int r = 0; r < 4; ++r)
          acc[i][r] = __builtin_amdgcn_mfma_f32_16x16x32_bf16(qf[i][kq], CUR[kq][r], acc[i][r], 0, 0, 0);
    for (int i = 0; i < 2; ++i)
      for (int jj = 0; jj < 4; ++jj) {
        int z = i * 4 + jj;
        l_run[z] += fexp2(acc[i][0][jj] * A2) + fexp2(acc[i][1][jj] * A2) +
                    fexp2(acc[i][2][jj] * A2) + fexp2(acc[i][3][jj] * A2);
      }
  };
  load_kf(kfA, w);
  p1body(0, kfA, kfB, true);
  p1body(1, kfB, kfA, true);
  p1body(2, kfA, kfB, true);
  p1body(3, kfB, kfA, true);
  p1body(4, kfA, kfB, true);
  p1body(5, kfB, kfA, true);
  p1body(6, kfA, kfB, true);
  p1body(7, kfB, kfA, false);

  for (int z = 0; z < 8; ++z) {
    float s = l_run[z];
    s += __shfl_xor(s, 1);
    s += __shfl_xor(s, 2);
    s += __shfl_xor(s, 4);
    s += __shfl_xor(s, 8);
    l_run[z] = s;
  }
  if (lr == 0)
    for (int i = 0; i < 2; ++i)
      for (int jj = 0; jj < 4; ++jj)
        Ls[w][i * 16 + lg * 4 + jj] = l_run[i * 4 + jj];
  barrier_lds_only();
  if (tid < 32)
    Linv[tid] = 1.0f / (Ls[0][tid] + Ls[1][tid] + Ls[2][tid] + Ls[3][tid]);
  barrier_lds_only();
  float invl[8];
  for (int i = 0; i < 2; ++i)
    for (int jj = 0; jj < 4; ++jj)
      invl[i * 4 + jj] = Linv[i * 16 + lg * 4 + jj];

  // ---- pass 2: kf 2-deep pipeline + early vf issue; 1KB-contiguous nt stores ----
  f32x4 cacc[2][4] = {};
  float* attn_row0 = attn + (size_t)bh * 2048 * 2048 + (size_t)q0 * 2048;

  auto p2body = [&](int g, bf16x8 (&CUR)[2][4], bf16x8 (&NXT)[2][4], bool pre) {
    int kt = g * 4 + w;
    // issue V fragments for THIS group now (consumed in PV, ~800 cyc later)
    bf16x8 vf[2][4];
    for (int kq2 = 0; kq2 < 2; ++kq2) {
      int kof = kq2 * 32 + lg * 8;
      for (int nn = 0; nn < 4; ++nn)
        vf[kq2][nn] = *(const bf16x8*)(Vh + (size_t)(nn * 16 + lr) * 2048 + kt * 64 + kof);
    }
    // issue K fragments for NEXT group (consumed one full group later)
    if (pre) load_kf(NXT, (g + 1) * 4 + w);
    f32x4 acc[2][4] = {};
    for (int kq = 0; kq < 2; ++kq)
      for (int i = 0; i < 2; ++i)
        for (int r = 0; r < 4; ++r)
          acc[i][r] = __builtin_amdgcn_mfma_f32_16x16x32_bf16(qf[i][kq], CUR[kq][r], acc[i][r], 0, 0, 0);
    for (int i = 0; i < 2; ++i)
      for (int r = 0; r < 4; ++r) {
        int col = w * 64 + r * 16 + lr;
        for (int jj = 0; jj < 4; ++jj) {
          int z = i * 4 + jj;
          int rl = i * 16 + lg * 4 + jj;
          Pf[rl * 260 + col] = fexp2(acc[i][r][jj] * A2) * invl[z];
        }
      }
    barrier_lds_only();
    for (int s = 0; s < 8; ++s) {
      int row = w * 8 + s;
      f32x4 v = *(const f32x4*)&Pf[row * 260 + lane * 4];
      __builtin_nontemporal_store(v,
          (f32x4*)(attn_row0 + (size_t)row * 2048 + g * 256 + lane * 4));
    }
    for (int kq2 = 0; kq2 < 2; ++kq2) {
      int kof = kq2 * 32 + lg * 8;
      bf16x8 pa[2];
      for (int i = 0; i < 2; ++i) {
        f32x4 plo = *(const f32x4*)&Pf[(i * 16 + lr) * 260 + w * 64 + kof];
        f32x4 phi = *(const f32x4*)&Pf[(i * 16 + lr) * 260 + w * 64 + kof + 4];
        pa[i] = pack8(plo, phi);
      }
      for (int i = 0; i < 2; ++i)
        for (int nn = 0; nn < 4; ++nn)
          cacc[i][nn] = __builtin_amdgcn_mfma_f32_16x16x32_bf16(pa[i], vf[kq2][nn], cacc[i][nn], 0, 0, 0);
    }
    barrier_lds_only();
  };
  load_kf(kfA, w);
  p2body(0, kfA, kfB, true);
  p2body(1, kfB, kfA, true);
  p2body(2, kfA, kfB, true);
  p2body(3, kfB, kfA, true);
  p2body(4, kfA, kfB, true);
  p2body(5, kfB, kfA, true);
  p2body(6, kfA, kfB, true);
  p2body(7, kfB, kfA, false);

  // ---- epilogue: cross-wave ctx reduce (deterministic w-order) ----
  float* Cs = Pf;  // reuse: 4*32*64 = 8192 floats <= 8320
  for (int i = 0; i < 2; ++i)
    for (int nn = 0; nn < 4; ++nn)
      for (int jj = 0; jj < 4; ++jj)
        Cs[w * 2048 + (i * 16 + lg * 4 + jj) * 64 + nn * 16 + lr] = cacc[i][nn][jj];
  barrier_lds_only();
  {
    int base = tid * 8;
    int row = base >> 6, d0 = base & 63;
    float v[8];
    for (int j = 0; j < 8; ++j) {
      float s = Cs[base + j] + Cs[2048 + base + j] + Cs[4096 + base + j] + Cs[6144 + base + j];
      v[j] = s;
    }
    union { unsigned short us[8]; bf16x8 b; } pk;
    for (int j = 0; j < 8; ++j) pk.us[j] = f2bf(v[j]);
    int tok = b_idx * 2048 + q0 + row;
    *(bf16x8*)(ctx + (size_t)tok * 1024 + h * 64 + d0) = pk.b;
  }
}

extern "C" void kernel_launch(void* const* d_in, const int* in_sizes, int n_in,
                              void* d_out, int out_size, void* d_ws, size_t ws_size,
                              hipStream_t stream) {
  const float* x    = (const float*)d_in[0];
  const float* Wqkv = (const float*)d_in[1];
  const float* bqkv = (const float*)d_in[2];
  const float* Wo   = (const float*)d_in[3];
  const float* bo   = (const float*)d_in[4];
  float* out  = (float*)d_out;
  float* attn = out + (size_t)4096 * 1024;

  char* ws = (char*)d_ws;
  unsigned short* xbf = (unsigned short*)(ws);              //  8 MB  [4096][1024]
  unsigned short* wqT = (unsigned short*)(ws + 8388608);    //  6 MB  [3072][1024]
  unsigned short* woT = (unsigned short*)(ws + 14680064);   //  2 MB  [1024][1024]
  unsigned short* Qb  = (unsigned short*)(ws + 16777216);   //  8 MB  [32][2048][64]
  unsigned short* Kb  = (unsigned short*)(ws + 25165824);   //  8 MB  [32][2048][64]
  unsigned short* Vt  = (unsigned short*)(ws + 33554432);   //  8 MB  [32][64][2048]
  unsigned short* ctx = (unsigned short*)(ws + 41943040);   //  8 MB  [4096][1024]

  k_cast_x<<<dim3(4096), dim3(256), 0, stream>>>(x, xbf, 1048576);
  k_transpose_w<<<dim3(16, 48), dim3(256), 0, stream>>>(Wqkv, wqT, 1024, 3072);
  k_transpose_w<<<dim3(16, 16), dim3(256), 0, stream>>>(Wo, woT, 1024, 1024);
  k_gemm<0><<<dim3(32, 24), dim3(256), 0, stream>>>(xbf, wqT, bqkv, Qb, Kb, Vt, nullptr);
  k_attn<<<dim3(2048), dim3(256), 0, stream>>>(Qb, Kb, Vt, attn, ctx);
  k_gemm<1><<<dim3(32, 8), dim3(256), 0, stream>>>(ctx, woT, bo, nullptr, nullptr, nullptr, out);
}

// Round 13
// 243.121 us; speedup vs baseline: 1.2684x; 1.2684x over previous
//
#include <hip/hip_runtime.h>
#include <stdint.h>

typedef __attribute__((ext_vector_type(8))) short bf16x8;
typedef __attribute__((ext_vector_type(4))) float f32x4;
typedef __attribute__((ext_vector_type(4))) unsigned int u32x4;
typedef __attribute__((ext_vector_type(4))) unsigned short u16x4;

#define DEVINL static __device__ __forceinline__

DEVINL unsigned short f2bf(float f) {
  uint32_t u = __builtin_bit_cast(uint32_t, f);
  u = (u + 0x7FFFu + ((u >> 16) & 1u)) >> 16;
  return (unsigned short)u;
}

DEVINL float fexp2(float x) {
#if __has_builtin(__builtin_amdgcn_exp2f)
  return __builtin_amdgcn_exp2f(x);
#else
  return __expf(x * 0.69314718056f);
#endif
}

// pack 8 fp32 -> 8 bf16 (RNE) via v_cvt_pk_bf16_f32 (register-only asm)
DEVINL bf16x8 pack8(f32x4 a, f32x4 b) {
  union { uint32_t u[4]; bf16x8 v; } r;
  asm("v_cvt_pk_bf16_f32 %0, %1, %2" : "=v"(r.u[0]) : "v"(a[0]), "v"(a[1]));
  asm("v_cvt_pk_bf16_f32 %0, %1, %2" : "=v"(r.u[1]) : "v"(a[2]), "v"(a[3]));
  asm("v_cvt_pk_bf16_f32 %0, %1, %2" : "=v"(r.u[2]) : "v"(b[0]), "v"(b[1]));
  asm("v_cvt_pk_bf16_f32 %0, %1, %2" : "=v"(r.u[3]) : "v"(b[2]), "v"(b[3]));
  return r.v;
}

// async global->LDS, 16B per lane; lds base must be wave-uniform (lane*16 implicit)
DEVINL void async16(const unsigned short* lds, const unsigned short* g) {
  __builtin_amdgcn_global_load_lds(
      (const __attribute__((address_space(1))) unsigned int*)g,
      (__attribute__((address_space(3))) unsigned int*)lds, 16, 0, 0);
}

// ---------------- cast x (fp32 -> bf16), vectorized ----------------
__global__ __launch_bounds__(256) void k_cast_x(const float* __restrict__ in,
                                                unsigned short* __restrict__ out, int n4) {
  int i = blockIdx.x * 256 + threadIdx.x;
  if (i >= n4) return;
  f32x4 v = *(const f32x4*)(in + (size_t)i * 4);
  u16x4 o;
  for (int j = 0; j < 4; ++j) o[j] = f2bf(v[j]);
  *(u16x4*)(out + (size_t)i * 4) = o;
}

// ------------- transpose-cast W: in [K][N] f32 -> out [N][K] bf16 -------------
__global__ __launch_bounds__(256) void k_transpose_w(const float* __restrict__ in,
                                                     unsigned short* __restrict__ out,
                                                     int K, int N) {
  __shared__ unsigned short tile[64][72];
  int k0 = blockIdx.x * 64, n0 = blockIdx.y * 64;
  int t = threadIdx.x;
  int r = t >> 2, c0 = (t & 3) * 16;
  for (int j = 0; j < 4; ++j) {
    int col = c0 + j * 4;
    f32x4 v = *(const f32x4*)(in + (size_t)(k0 + r) * N + n0 + col);
    u16x4 o;
    for (int q = 0; q < 4; ++q) o[q] = f2bf(v[q]);
    *(u16x4*)(&tile[r][col]) = o;
  }
  __syncthreads();
  for (int j = 0; j < 4; ++j) {
    int kcol = c0 + j * 4;
    u16x4 o;
    for (int q = 0; q < 4; ++q) o[q] = tile[kcol + q][r];
    *(u16x4*)(out + (size_t)(n0 + r) * K + k0 + kcol) = o;
  }
}

// ---------------- GEMM: A[M][1024] bf16  x  Bt[N][1024] bf16 ----------------
template <int MODE>
__global__ __launch_bounds__(256) void k_gemm(const unsigned short* __restrict__ A,
                                              const unsigned short* __restrict__ Bt,
                                              const float* __restrict__ bias,
                                              unsigned short* __restrict__ Qb,
                                              unsigned short* __restrict__ Kb,
                                              unsigned short* __restrict__ Vt,
                                              float* __restrict__ outF) {
  constexpr int KD = 1024;
  __shared__ unsigned short sh[17408];
  unsigned short* lA = sh;
  unsigned short* lB = sh + 8192;
  int tid = threadIdx.x;
  int lane = tid & 63, w = tid >> 6;
  int wr = w >> 1, wc = w & 1;
  int m0 = blockIdx.x * 128, n0 = blockIdx.y * 128;
  int lr = lane & 15, lg = lane >> 4;

  f32x4 acc[4][4] = {};

  int srow = w * 32 + (lane >> 3);
  int scol = (lane & 7) * 8;
  const unsigned short* gA = A + (size_t)(m0 + srow) * KD + scol;
  const unsigned short* gB = Bt + (size_t)(n0 + srow) * KD + scol;

  for (int kk = 0; kk < KD; kk += 64) {
    for (int s = 0; s < 4; ++s) {
      async16(&lA[(w * 32 + s * 8) * 64], gA + (size_t)s * 8 * KD + kk);
      async16(&lB[(w * 32 + s * 8) * 64], gB + (size_t)s * 8 * KD + kk);
    }
    __syncthreads();
    for (int kq = 0; kq < 2; ++kq) {
      bf16x8 af[4], bfr[4];
      for (int i = 0; i < 4; ++i)
        af[i] = *(const bf16x8*)(&lA[(wr * 64 + i * 16 + lr) * 64 + (kq * 4 + lg) * 8]);
      for (int r = 0; r < 4; ++r)
        bfr[r] = *(const bf16x8*)(&lB[(wc * 64 + r * 16 + lr) * 64 + (kq * 4 + lg) * 8]);
      for (int i = 0; i < 4; ++i)
        for (int r = 0; r < 4; ++r)
          acc[i][r] = __builtin_amdgcn_mfma_f32_16x16x32_bf16(af[i], bfr[r], acc[i][r], 0, 0, 0);
    }
    __syncthreads();
  }

  if (MODE == 0) {
    int which = n0 >> 10;
    int head0 = (n0 & 1023) >> 6;
    int b_idx = m0 >> 11;
    int l0 = m0 & 2047;
    if (which < 2) {
      for (int r = 0; r < 4; ++r) {
        int nl = wc * 64 + r * 16 + lr;
        float bv = bias[n0 + nl];
        for (int i = 0; i < 4; ++i) {
          int mlb = wr * 64 + i * 16 + lg * 4;
          for (int jj = 0; jj < 4; ++jj)
            sh[(mlb + jj) * 136 + nl] = f2bf(acc[i][r][jj] + bv);
        }
      }
      __syncthreads();
      unsigned short* dst = (which == 0) ? Qb : Kb;
      for (int it = 0; it < 4; ++it) {
        int row = it * 64 + (tid >> 2);
        int ml = row & 127, hd = row >> 7;
        int c = (tid & 3) * 16;
        bf16x8 v0 = *(const bf16x8*)&sh[ml * 136 + hd * 64 + c];
        bf16x8 v1 = *(const bf16x8*)&sh[ml * 136 + hd * 64 + c + 8];
        size_t bh = (size_t)(b_idx * 16 + head0 + hd);
        size_t off = (bh * 2048 + l0 + ml) * 64 + c;
        *(bf16x8*)(dst + off) = v0;
        *(bf16x8*)(dst + off + 8) = v1;
      }
    } else {
      for (int r = 0; r < 4; ++r) {
        int nl = wc * 64 + r * 16 + lr;
        float bv = bias[n0 + nl];
        for (int i = 0; i < 4; ++i) {
          int mlb = wr * 64 + i * 16 + lg * 4;
          u16x4 pk;
          for (int jj = 0; jj < 4; ++jj) pk[jj] = f2bf(acc[i][r][jj] + bv);
          *(u16x4*)&sh[nl * 136 + mlb] = pk;
        }
      }
      __syncthreads();
      for (int it = 0; it < 4; ++it) {
        int nl = it * 32 + (tid >> 3);
        int c = (tid & 7) * 16;
        bf16x8 v0 = *(const bf16x8*)&sh[nl * 136 + c];
        bf16x8 v1 = *(const bf16x8*)&sh[nl * 136 + c + 8];
        int dk = nl & 63, hd = nl >> 6;
        size_t bh = (size_t)(b_idx * 16 + head0 + hd);
        size_t off = (bh * 64 + dk) * 2048 + l0 + c;
        *(bf16x8*)(Vt + off) = v0;
        *(bf16x8*)(Vt + off + 8) = v1;
      }
    }
  } else {
    for (int r = 0; r < 4; ++r) {
      int n = n0 + wc * 64 + r * 16 + lr;
      float bv = bias[n];
      for (int i = 0; i < 4; ++i) {
        int mb = m0 + wr * 64 + i * 16 + lg * 4;
        for (int jj = 0; jj < 4; ++jj)
          outF[(size_t)(mb + jj) * 1024 + n] = acc[i][r][jj] + bv;
      }
    }
  }
}

// ---------------- fused attention (v5: GEMM-mold LDS staging) ----------------
// R7 wave geometry + numerics (4 waves x 32 q-rows, XCD swizzle), but K/V^T
// tiles staged into LDS per 64-key step via global_load_lds with both-sides
// chunk-XOR (c ^= row&7); fragments via conflict-free ds_read_b128, 4x shared
// across waves. Conservative m97 protocol: single buffer, stage at loop top,
// plain __syncthreads x2 per kt. Pass1 and pass2 read K through the identical
// LDS path -> S bit-identical -> exact normalization.
__global__ __launch_bounds__(256) void k_attn(const unsigned short* __restrict__ Qb,
                                              const unsigned short* __restrict__ Kb,
                                              const unsigned short* __restrict__ Vt,
                                              float* __restrict__ attn,
                                              unsigned short* __restrict__ ctx) {
  __shared__ unsigned short Ks[64 * 64];   //  8 KB: [key][d], chunk-XOR swizzled
  __shared__ unsigned short Vs[64 * 64];   //  8 KB: [dk][key], chunk-XOR swizzled
  __shared__ float Pf[4][32 * 68];         // ~35 KB per-wave P tiles
  int tid = threadIdx.x, lane = tid & 63, w = tid >> 6;
  int lr = lane & 15, lg = lane >> 4;
  int bid = blockIdx.x;
  int xcd = bid & 7, slot = bid >> 3;
  int bh = xcd * 4 + (slot >> 4);          // 4 heads per XCD -> K/V L2-resident
  int qb = slot & 15;
  int q0 = qb * 128 + w * 32;
  int b_idx = bh >> 4, h = bh & 15;
  const unsigned short* Qh = Qb + (size_t)bh * 2048 * 64;
  const unsigned short* Kh = Kb + (size_t)bh * 2048 * 64;
  const unsigned short* Vh = Vt + (size_t)bh * 64 * 2048;
  float* Pw = &Pf[w][0];
  const float A2 = 0.125f * 1.44269504089f;  // scale * log2(e)
  int e7 = lr & 7;                            // read-side swizzle key (row&7 == lr&7)

  // staging source pointers (pre-swizzled chunk; rule #21 both-sides involution)
  int srow = w * 8 + (lane >> 3);            // rows 0..31 (call 0), +32 (call 1)
  int sc = (lane & 7) ^ (srow & 7);          // (srow+32)&7 == srow&7, same sc
  const unsigned short* gK = Kh + (size_t)srow * 64 + sc * 8;
  const unsigned short* gV = Vh + (size_t)srow * 2048 + sc * 8;

  bf16x8 qf[2][2];
  for (int i = 0; i < 2; ++i)
    for (int kq = 0; kq < 2; ++kq)
      qf[i][kq] = *(const bf16x8*)(Qh + (size_t)(q0 + i * 16 + lr) * 64 + kq * 32 + lg * 8);

  float l_run[8] = {0.f, 0.f, 0.f, 0.f, 0.f, 0.f, 0.f, 0.f};

  // ---- pass 1: per-lane partial sum of exp2(s*A2); K from LDS ----
  for (int kt = 0; kt < 32; ++kt) {
    async16(&Ks[(w * 8) * 64],       gK + (size_t)kt * 4096);
    async16(&Ks[((w + 4) * 8) * 64], gK + (size_t)kt * 4096 + 2048);
    __syncthreads();
    f32x4 acc[2][4] = {};
    for (int kq = 0; kq < 2; ++kq) {
      int j = kq * 4 + lg;
      bf16x8 kf[4];
      for (int r = 0; r < 4; ++r)
        kf[r] = *(const bf16x8*)&Ks[(r * 16 + lr) * 64 + ((j ^ e7) << 3)];
      for (int i = 0; i < 2; ++i)
        for (int r = 0; r < 4; ++r)
          acc[i][r] = __builtin_amdgcn_mfma_f32_16x16x32_bf16(qf[i][kq], kf[r], acc[i][r], 0, 0, 0);
    }
    for (int i = 0; i < 2; ++i)
      for (int jj = 0; jj < 4; ++jj) {
        int z = i * 4 + jj;
        l_run[z] += fexp2(acc[i][0][jj] * A2) + fexp2(acc[i][1][jj] * A2) +
                    fexp2(acc[i][2][jj] * A2) + fexp2(acc[i][3][jj] * A2);
      }
    __syncthreads();
  }
  float invl[8];
  for (int z = 0; z < 8; ++z) {
    float s = l_run[z];
    s += __shfl_xor(s, 1);
    s += __shfl_xor(s, 2);
    s += __shfl_xor(s, 4);
    s += __shfl_xor(s, 8);
    invl[z] = 1.0f / s;
  }

  // ---- pass 2: recompute S (same LDS path), write attn, PV from LDS ----
  f32x4 cacc[2][4] = {};
  float* attn_base = attn + (size_t)bh * 2048 * 2048;
  float* arow = attn_base + (size_t)(q0 + lg) * 2048 + lr * 4;

  for (int kt = 0; kt < 32; ++kt) {
    async16(&Ks[(w * 8) * 64],       gK + (size_t)kt * 4096);
    async16(&Ks[((w + 4) * 8) * 64], gK + (size_t)kt * 4096 + 2048);
    async16(&Vs[(w * 8) * 64],       gV + (size_t)kt * 64);
    async16(&Vs[((w + 4) * 8) * 64], gV + (size_t)kt * 64 + 65536);
    __syncthreads();
    f32x4 acc[2][4] = {};
    for (int kq = 0; kq < 2; ++kq) {
      int j = kq * 4 + lg;
      bf16x8 kf[4];
      for (int r = 0; r < 4; ++r)
        kf[r] = *(const bf16x8*)&Ks[(r * 16 + lr) * 64 + ((j ^ e7) << 3)];
      for (int i = 0; i < 2; ++i)
        for (int r = 0; r < 4; ++r)
          acc[i][r] = __builtin_amdgcn_mfma_f32_16x16x32_bf16(qf[i][kq], kf[r], acc[i][r], 0, 0, 0);
    }
    // p -> per-wave fp32 LDS tile (no cross-wave sharing -> no extra barrier)
    for (int i = 0; i < 2; ++i)
      for (int r = 0; r < 4; ++r) {
        int key = r * 16 + lr;
        for (int jj = 0; jj < 4; ++jj) {
          int z = i * 4 + jj;
          int rl = i * 16 + lg * 4 + jj;
          Pw[rl * 68 + key] = fexp2(acc[i][r][jj] * A2) * invl[z];
        }
      }
    // coalesced attn write: 8 x f32x4 per lane, 256B contiguous per row
    for (int s = 0; s < 8; ++s) {
      f32x4 v = *(const f32x4*)(&Pw[(s * 4 + lg) * 68 + lr * 4]);
      __builtin_nontemporal_store(v, (f32x4*)(arow + (size_t)s * 4 * 2048 + kt * 64));
    }
    // PV: A = P (fp32 tile -> cvt_pk bf16), B = V from LDS
    for (int kq2 = 0; kq2 < 2; ++kq2) {
      int j = kq2 * 4 + lg;
      int kof = kq2 * 32 + lg * 8;
      bf16x8 pa[2], vf[4];
      for (int i = 0; i < 2; ++i) {
        f32x4 plo = *(const f32x4*)(&Pw[(i * 16 + lr) * 68 + kof]);
        f32x4 phi = *(const f32x4*)(&Pw[(i * 16 + lr) * 68 + kof + 4]);
        pa[i] = pack8(plo, phi);
      }
      for (int nn = 0; nn < 4; ++nn)
        vf[nn] = *(const bf16x8*)&Vs[(nn * 16 + lr) * 64 + ((j ^ e7) << 3)];
      for (int i = 0; i < 2; ++i)
        for (int nn = 0; nn < 4; ++nn)
          cacc[i][nn] = __builtin_amdgcn_mfma_f32_16x16x32_bf16(pa[i], vf[nn], cacc[i][nn], 0, 0, 0);
    }
    __syncthreads();
  }

  for (int nn = 0; nn < 4; ++nn) {
    int d = nn * 16 + lr;
    for (int i = 0; i < 2; ++i)
      for (int jj = 0; jj < 4; ++jj) {
        int q = q0 + i * 16 + lg * 4 + jj;
        int tok = b_idx * 2048 + q;
        ctx[(size_t)tok * 1024 + h * 64 + d] = f2bf(cacc[i][nn][jj]);
      }
  }
}

extern "C" void kernel_launch(void* const* d_in, const int* in_sizes, int n_in,
                              void* d_out, int out_size, void* d_ws, size_t ws_size,
                              hipStream_t stream) {
  const float* x    = (const float*)d_in[0];
  const float* Wqkv = (const float*)d_in[1];
  const float* bqkv = (const float*)d_in[2];
  const float* Wo   = (const float*)d_in[3];
  const float* bo   = (const float*)d_in[4];
  float* out  = (float*)d_out;
  float* attn = out + (size_t)4096 * 1024;

  char* ws = (char*)d_ws;
  unsigned short* xbf = (unsigned short*)(ws);              //  8 MB  [4096][1024]
  unsigned short* wqT = (unsigned short*)(ws + 8388608);    //  6 MB  [3072][1024]
  unsigned short* woT = (unsigned short*)(ws + 14680064);   //  2 MB  [1024][1024]
  unsigned short* Qb  = (unsigned short*)(ws + 16777216);   //  8 MB  [32][2048][64]
  unsigned short* Kb  = (unsigned short*)(ws + 25165824);   //  8 MB  [32][2048][64]
  unsigned short* Vt  = (unsigned short*)(ws + 33554432);   //  8 MB  [32][64][2048]
  unsigned short* ctx = (unsigned short*)(ws + 41943040);   //  8 MB  [4096][1024]

  k_cast_x<<<dim3(4096), dim3(256), 0, stream>>>(x, xbf, 1048576);
  k_transpose_w<<<dim3(16, 48), dim3(256), 0, stream>>>(Wqkv, wqT, 1024, 3072);
  k_transpose_w<<<dim3(16, 16), dim3(256), 0, stream>>>(Wo, woT, 1024, 1024);
  k_gemm<0><<<dim3(32, 24), dim3(256), 0, stream>>>(xbf, wqT, bqkv, Qb, Kb, Vt, nullptr);
  k_attn<<<dim3(512), dim3(256), 0, stream>>>(Qb, Kb, Vt, attn, ctx);
  k_gemm<1><<<dim3(32, 8), dim3(256), 0, stream>>>(ctx, woT, bo, nullptr, nullptr, nullptr, out);
}

// Round 14
// 240.256 us; speedup vs baseline: 1.2835x; 1.0119x over previous
//
#include <hip/hip_runtime.h>
#include <stdint.h>

typedef __attribute__((ext_vector_type(8))) short bf16x8;
typedef __attribute__((ext_vector_type(4))) float f32x4;
typedef __attribute__((ext_vector_type(4))) unsigned int u32x4;
typedef __attribute__((ext_vector_type(4))) unsigned short u16x4;

#define DEVINL static __device__ __forceinline__

DEVINL unsigned short f2bf(float f) {
  uint32_t u = __builtin_bit_cast(uint32_t, f);
  u = (u + 0x7FFFu + ((u >> 16) & 1u)) >> 16;
  return (unsigned short)u;
}

DEVINL float fexp2(float x) {
#if __has_builtin(__builtin_amdgcn_exp2f)
  return __builtin_amdgcn_exp2f(x);
#else
  return __expf(x * 0.69314718056f);
#endif
}

DEVINL void raw_barrier() {
  __builtin_amdgcn_sched_barrier(0);
  __builtin_amdgcn_s_barrier();
  __builtin_amdgcn_sched_barrier(0);
}

// barrier B: order LDS ops, then block barrier (stores stay in flight)
DEVINL void barrier_lds_only() {
  asm volatile("s_waitcnt lgkmcnt(0)" ::: "memory");
  raw_barrier();
}

// pack 8 fp32 -> 8 bf16 (RNE) via v_cvt_pk_bf16_f32 (register-only asm)
DEVINL bf16x8 pack8(f32x4 a, f32x4 b) {
  union { uint32_t u[4]; bf16x8 v; } r;
  asm("v_cvt_pk_bf16_f32 %0, %1, %2" : "=v"(r.u[0]) : "v"(a[0]), "v"(a[1]));
  asm("v_cvt_pk_bf16_f32 %0, %1, %2" : "=v"(r.u[1]) : "v"(a[2]), "v"(a[3]));
  asm("v_cvt_pk_bf16_f32 %0, %1, %2" : "=v"(r.u[2]) : "v"(b[0]), "v"(b[1]));
  asm("v_cvt_pk_bf16_f32 %0, %1, %2" : "=v"(r.u[3]) : "v"(b[2]), "v"(b[3]));
  return r.v;
}

// async global->LDS, 16B per lane; lds base must be wave-uniform (lane*16 implicit)
DEVINL void async16(const unsigned short* lds, const unsigned short* g) {
  __builtin_amdgcn_global_load_lds(
      (const __attribute__((address_space(1))) unsigned int*)g,
      (__attribute__((address_space(3))) unsigned int*)lds, 16, 0, 0);
}

// ---------------- cast x (fp32 -> bf16), vectorized ----------------
__global__ __launch_bounds__(256) void k_cast_x(const float* __restrict__ in,
                                                unsigned short* __restrict__ out, int n4) {
  int i = blockIdx.x * 256 + threadIdx.x;
  if (i >= n4) return;
  f32x4 v = *(const f32x4*)(in + (size_t)i * 4);
  u16x4 o;
  for (int j = 0; j < 4; ++j) o[j] = f2bf(v[j]);
  *(u16x4*)(out + (size_t)i * 4) = o;
}

// ------------- transpose-cast W: in [K][N] f32 -> out [N][K] bf16 -------------
__global__ __launch_bounds__(256) void k_transpose_w(const float* __restrict__ in,
                                                     unsigned short* __restrict__ out,
                                                     int K, int N) {
  __shared__ unsigned short tile[64][72];
  int k0 = blockIdx.x * 64, n0 = blockIdx.y * 64;
  int t = threadIdx.x;
  int r = t >> 2, c0 = (t & 3) * 16;
  for (int j = 0; j < 4; ++j) {
    int col = c0 + j * 4;
    f32x4 v = *(const f32x4*)(in + (size_t)(k0 + r) * N + n0 + col);
    u16x4 o;
    for (int q = 0; q < 4; ++q) o[q] = f2bf(v[q]);
    *(u16x4*)(&tile[r][col]) = o;
  }
  __syncthreads();
  for (int j = 0; j < 4; ++j) {
    int kcol = c0 + j * 4;
    u16x4 o;
    for (int q = 0; q < 4; ++q) o[q] = tile[kcol + q][r];
    *(u16x4*)(out + (size_t)(n0 + r) * K + k0 + kcol) = o;
  }
}

// ---------------- GEMM: A[M][1024] bf16  x  Bt[N][1024] bf16 ----------------
template <int MODE>
__global__ __launch_bounds__(256) void k_gemm(const unsigned short* __restrict__ A,
                                              const unsigned short* __restrict__ Bt,
                                              const float* __restrict__ bias,
                                              unsigned short* __restrict__ Qb,
                                              unsigned short* __restrict__ Kb,
                                              unsigned short* __restrict__ Vt,
                                              float* __restrict__ outF) {
  constexpr int KD = 1024;
  __shared__ unsigned short sh[17408];
  unsigned short* lA = sh;
  unsigned short* lB = sh + 8192;
  int tid = threadIdx.x;
  int lane = tid & 63, w = tid >> 6;
  int wr = w >> 1, wc = w & 1;
  int m0 = blockIdx.x * 128, n0 = blockIdx.y * 128;
  int lr = lane & 15, lg = lane >> 4;

  f32x4 acc[4][4] = {};

  int srow = w * 32 + (lane >> 3);
  int scol = (lane & 7) * 8;
  const unsigned short* gA = A + (size_t)(m0 + srow) * KD + scol;
  const unsigned short* gB = Bt + (size_t)(n0 + srow) * KD + scol;

  for (int kk = 0; kk < KD; kk += 64) {
    for (int s = 0; s < 4; ++s) {
      async16(&lA[(w * 32 + s * 8) * 64], gA + (size_t)s * 8 * KD + kk);
      async16(&lB[(w * 32 + s * 8) * 64], gB + (size_t)s * 8 * KD + kk);
    }
    __syncthreads();
    for (int kq = 0; kq < 2; ++kq) {
      bf16x8 af[4], bfr[4];
      for (int i = 0; i < 4; ++i)
        af[i] = *(const bf16x8*)(&lA[(wr * 64 + i * 16 + lr) * 64 + (kq * 4 + lg) * 8]);
      for (int r = 0; r < 4; ++r)
        bfr[r] = *(const bf16x8*)(&lB[(wc * 64 + r * 16 + lr) * 64 + (kq * 4 + lg) * 8]);
      for (int i = 0; i < 4; ++i)
        for (int r = 0; r < 4; ++r)
          acc[i][r] = __builtin_amdgcn_mfma_f32_16x16x32_bf16(af[i], bfr[r], acc[i][r], 0, 0, 0);
    }
    __syncthreads();
  }

  if (MODE == 0) {
    int which = n0 >> 10;
    int head0 = (n0 & 1023) >> 6;
    int b_idx = m0 >> 11;
    int l0 = m0 & 2047;
    if (which < 2) {
      for (int r = 0; r < 4; ++r) {
        int nl = wc * 64 + r * 16 + lr;
        float bv = bias[n0 + nl];
        for (int i = 0; i < 4; ++i) {
          int mlb = wr * 64 + i * 16 + lg * 4;
          for (int jj = 0; jj < 4; ++jj)
            sh[(mlb + jj) * 136 + nl] = f2bf(acc[i][r][jj] + bv);
        }
      }
      __syncthreads();
      unsigned short* dst = (which == 0) ? Qb : Kb;
      for (int it = 0; it < 4; ++it) {
        int row = it * 64 + (tid >> 2);
        int ml = row & 127, hd = row >> 7;
        int c = (tid & 3) * 16;
        bf16x8 v0 = *(const bf16x8*)&sh[ml * 136 + hd * 64 + c];
        bf16x8 v1 = *(const bf16x8*)&sh[ml * 136 + hd * 64 + c + 8];
        size_t bh = (size_t)(b_idx * 16 + head0 + hd);
        size_t off = (bh * 2048 + l0 + ml) * 64 + c;
        *(bf16x8*)(dst + off) = v0;
        *(bf16x8*)(dst + off + 8) = v1;
      }
    } else {
      for (int r = 0; r < 4; ++r) {
        int nl = wc * 64 + r * 16 + lr;
        float bv = bias[n0 + nl];
        for (int i = 0; i < 4; ++i) {
          int mlb = wr * 64 + i * 16 + lg * 4;
          u16x4 pk;
          for (int jj = 0; jj < 4; ++jj) pk[jj] = f2bf(acc[i][r][jj] + bv);
          *(u16x4*)&sh[nl * 136 + mlb] = pk;
        }
      }
      __syncthreads();
      for (int it = 0; it < 4; ++it) {
        int nl = it * 32 + (tid >> 3);
        int c = (tid & 7) * 16;
        bf16x8 v0 = *(const bf16x8*)&sh[nl * 136 + c];
        bf16x8 v1 = *(const bf16x8*)&sh[nl * 136 + c + 8];
        int dk = nl & 63, hd = nl >> 6;
        size_t bh = (size_t)(b_idx * 16 + head0 + hd);
        size_t off = (bh * 64 + dk) * 2048 + l0 + c;
        *(bf16x8*)(Vt + off) = v0;
        *(bf16x8*)(Vt + off + 8) = v1;
      }
    }
  } else {
    for (int r = 0; r < 4; ++r) {
      int n = n0 + wc * 64 + r * 16 + lr;
      float bv = bias[n];
      for (int i = 0; i < 4; ++i) {
        int mb = m0 + wr * 64 + i * 16 + lg * 4;
        for (int jj = 0; jj < 4; ++jj)
          outF[(size_t)(mb + jj) * 1024 + n] = acc[i][r][jj] + bv;
      }
    }
  }
}

// ---------------- fused attention (v6: R13 + double-buffered staging, counted vmcnt) ----------------
// Same math/order as R13 (bit-identical). K/V tiles double-buffered; iteration
// kt stages kt+1's tiles then waits a COUNTED vmcnt so the current tile is
// ready while next-stage + prior stores stay in flight. Raw s_barrier (no
// vmcnt drain). Per-wave vmem accounting:
//   p1 iter: 2 stage ops -> wait vmcnt(2) (last: 0)
//   p2 iter: 4 stage + 8 nt stores -> wait vmcnt(12) (kt=0: 4, kt=31: 8)
__global__ __launch_bounds__(256) void k_attn(const unsigned short* __restrict__ Qb,
                                              const unsigned short* __restrict__ Kb,
                                              const unsigned short* __restrict__ Vt,
                                              float* __restrict__ attn,
                                              unsigned short* __restrict__ ctx) {
  __shared__ unsigned short Ks[2][4096];   // 16 KB: [key][d], chunk-XOR swizzled
  __shared__ unsigned short Vs[2][4096];   // 16 KB: [dk][key], chunk-XOR swizzled
  __shared__ float Pf[4][32 * 68];         // ~35 KB per-wave P tiles
  int tid = threadIdx.x, lane = tid & 63, w = tid >> 6;
  int lr = lane & 15, lg = lane >> 4;
  int bid = blockIdx.x;
  int xcd = bid & 7, slot = bid >> 3;
  int bh = xcd * 4 + (slot >> 4);          // 4 heads per XCD -> K/V L2-resident
  int qb = slot & 15;
  int q0 = qb * 128 + w * 32;
  int b_idx = bh >> 4, h = bh & 15;
  const unsigned short* Qh = Qb + (size_t)bh * 2048 * 64;
  const unsigned short* Kh = Kb + (size_t)bh * 2048 * 64;
  const unsigned short* Vh = Vt + (size_t)bh * 64 * 2048;
  float* Pw = &Pf[w][0];
  const float A2 = 0.125f * 1.44269504089f;  // scale * log2(e)
  int e7 = lr & 7;                            // read-side swizzle key (row&7 == lr&7)

  // staging source pointers (pre-swizzled chunk; both-sides involution)
  int srow = w * 8 + (lane >> 3);            // rows 0..31 (call 0), +32 (call 1)
  int sc = (lane & 7) ^ (srow & 7);          // (srow+32)&7 == srow&7, same sc
  const unsigned short* gK = Kh + (size_t)srow * 64 + sc * 8;
  const unsigned short* gV = Vh + (size_t)srow * 2048 + sc * 8;

  bf16x8 qf[2][2];
  for (int i = 0; i < 2; ++i)
    for (int kq = 0; kq < 2; ++kq)
      qf[i][kq] = *(const bf16x8*)(Qh + (size_t)(q0 + i * 16 + lr) * 64 + kq * 32 + lg * 8);

  float l_run[8] = {0.f, 0.f, 0.f, 0.f, 0.f, 0.f, 0.f, 0.f};

  // ---- pass 1: K double-buffered, counted vmcnt ----
  async16(&Ks[0][(w * 8) * 64],       gK);
  async16(&Ks[0][((w + 4) * 8) * 64], gK + 2048);
  for (int kt = 0; kt < 32; ++kt) {
    int cur = kt & 1;
    if (kt < 31) {
      async16(&Ks[cur ^ 1][(w * 8) * 64],       gK + (size_t)(kt + 1) * 4096);
      async16(&Ks[cur ^ 1][((w + 4) * 8) * 64], gK + (size_t)(kt + 1) * 4096 + 2048);
      asm volatile("s_waitcnt vmcnt(2)" ::: "memory");
    } else {
      asm volatile("s_waitcnt vmcnt(0)" ::: "memory");
    }
    raw_barrier();                          // barrier A: current K tile ready
    f32x4 acc[2][4] = {};
    for (int kq = 0; kq < 2; ++kq) {
      int j = kq * 4 + lg;
      bf16x8 kf[4];
      for (int r = 0; r < 4; ++r)
        kf[r] = *(const bf16x8*)&Ks[cur][(r * 16 + lr) * 64 + ((j ^ e7) << 3)];
      for (int i = 0; i < 2; ++i)
        for (int r = 0; r < 4; ++r)
          acc[i][r] = __builtin_amdgcn_mfma_f32_16x16x32_bf16(qf[i][kq], kf[r], acc[i][r], 0, 0, 0);
    }
    for (int i = 0; i < 2; ++i)
      for (int jj = 0; jj < 4; ++jj) {
        int z = i * 4 + jj;
        l_run[z] += fexp2(acc[i][0][jj] * A2) + fexp2(acc[i][1][jj] * A2) +
                    fexp2(acc[i][2][jj] * A2) + fexp2(acc[i][3][jj] * A2);
      }
    barrier_lds_only();                     // barrier B: reads done before overwrite
  }
  float invl[8];
  for (int z = 0; z < 8; ++z) {
    float s = l_run[z];
    s += __shfl_xor(s, 1);
    s += __shfl_xor(s, 2);
    s += __shfl_xor(s, 4);
    s += __shfl_xor(s, 8);
    invl[z] = 1.0f / s;
  }

  // ---- pass 2: K+V double-buffered, counted vmcnt; stores never drained in-loop ----
  f32x4 cacc[2][4] = {};
  float* attn_base = attn + (size_t)bh * 2048 * 2048;
  float* arow = attn_base + (size_t)(q0 + lg) * 2048 + lr * 4;

  async16(&Ks[0][(w * 8) * 64],       gK);
  async16(&Ks[0][((w + 4) * 8) * 64], gK + 2048);
  async16(&Vs[0][(w * 8) * 64],       gV);
  async16(&Vs[0][((w + 4) * 8) * 64], gV + 65536);
  for (int kt = 0; kt < 32; ++kt) {
    int cur = kt & 1;
    if (kt < 31) {
      async16(&Ks[cur ^ 1][(w * 8) * 64],       gK + (size_t)(kt + 1) * 4096);
      async16(&Ks[cur ^ 1][((w + 4) * 8) * 64], gK + (size_t)(kt + 1) * 4096 + 2048);
      async16(&Vs[cur ^ 1][(w * 8) * 64],       gV + (size_t)(kt + 1) * 64);
      async16(&Vs[cur ^ 1][((w + 4) * 8) * 64], gV + (size_t)(kt + 1) * 64 + 65536);
    }
    if (kt == 0)       asm volatile("s_waitcnt vmcnt(4)" ::: "memory");
    else if (kt == 31) asm volatile("s_waitcnt vmcnt(8)" ::: "memory");
    else               asm volatile("s_waitcnt vmcnt(12)" ::: "memory");
    raw_barrier();                          // barrier A: current K/V tiles ready
    f32x4 acc[2][4] = {};
    for (int kq = 0; kq < 2; ++kq) {
      int j = kq * 4 + lg;
      bf16x8 kf[4];
      for (int r = 0; r < 4; ++r)
        kf[r] = *(const bf16x8*)&Ks[cur][(r * 16 + lr) * 64 + ((j ^ e7) << 3)];
      for (int i = 0; i < 2; ++i)
        for (int r = 0; r < 4; ++r)
          acc[i][r] = __builtin_amdgcn_mfma_f32_16x16x32_bf16(qf[i][kq], kf[r], acc[i][r], 0, 0, 0);
    }
    // p -> per-wave fp32 LDS tile (same-wave in-order LDS: no barrier needed)
    for (int i = 0; i < 2; ++i)
      for (int r = 0; r < 4; ++r) {
        int key = r * 16 + lr;
        for (int jj = 0; jj < 4; ++jj) {
          int z = i * 4 + jj;
          int rl = i * 16 + lg * 4 + jj;
          Pw[rl * 68 + key] = fexp2(acc[i][r][jj] * A2) * invl[z];
        }
      }
    // coalesced attn write: 8 x f32x4 per lane, 256B contiguous per row
    for (int s = 0; s < 8; ++s) {
      f32x4 v = *(const f32x4*)(&Pw[(s * 4 + lg) * 68 + lr * 4]);
      __builtin_nontemporal_store(v, (f32x4*)(arow + (size_t)s * 4 * 2048 + kt * 64));
    }
    // PV: A = P (fp32 tile -> cvt_pk bf16), B = V from LDS
    for (int kq2 = 0; kq2 < 2; ++kq2) {
      int j = kq2 * 4 + lg;
      int kof = kq2 * 32 + lg * 8;
      bf16x8 pa[2], vf[4];
      for (int i = 0; i < 2; ++i) {
        f32x4 plo = *(const f32x4*)(&Pw[(i * 16 + lr) * 68 + kof]);
        f32x4 phi = *(const f32x4*)(&Pw[(i * 16 + lr) * 68 + kof + 4]);
        pa[i] = pack8(plo, phi);
      }
      for (int nn = 0; nn < 4; ++nn)
        vf[nn] = *(const bf16x8*)&Vs[cur][(nn * 16 + lr) * 64 + ((j ^ e7) << 3)];
      for (int i = 0; i < 2; ++i)
        for (int nn = 0; nn < 4; ++nn)
          cacc[i][nn] = __builtin_amdgcn_mfma_f32_16x16x32_bf16(pa[i], vf[nn], cacc[i][nn], 0, 0, 0);
    }
    barrier_lds_only();                     // barrier B: reads done before overwrite
  }

  for (int nn = 0; nn < 4; ++nn) {
    int d = nn * 16 + lr;
    for (int i = 0; i < 2; ++i)
      for (int jj = 0; jj < 4; ++jj) {
        int q = q0 + i * 16 + lg * 4 + jj;
        int tok = b_idx * 2048 + q;
        ctx[(size_t)tok * 1024 + h * 64 + d] = f2bf(cacc[i][nn][jj]);
      }
  }
}

extern "C" void kernel_launch(void* const* d_in, const int* in_sizes, int n_in,
                              void* d_out, int out_size, void* d_ws, size_t ws_size,
                              hipStream_t stream) {
  const float* x    = (const float*)d_in[0];
  const float* Wqkv = (const float*)d_in[1];
  const float* bqkv = (const float*)d_in[2];
  const float* Wo   = (const float*)d_in[3];
  const float* bo   = (const float*)d_in[4];
  float* out  = (float*)d_out;
  float* attn = out + (size_t)4096 * 1024;

  char* ws = (char*)d_ws;
  unsigned short* xbf = (unsigned short*)(ws);              //  8 MB  [4096][1024]
  unsigned short* wqT = (unsigned short*)(ws + 8388608);    //  6 MB  [3072][1024]
  unsigned short* woT = (unsigned short*)(ws + 14680064);   //  2 MB  [1024][1024]
  unsigned short* Qb  = (unsigned short*)(ws + 16777216);   //  8 MB  [32][2048][64]
  unsigned short* Kb  = (unsigned short*)(ws + 25165824);   //  8 MB  [32][2048][64]
  unsigned short* Vt  = (unsigned short*)(ws + 33554432);   //  8 MB  [32][64][2048]
  unsigned short* ctx = (unsigned short*)(ws + 41943040);   //  8 MB  [4096][1024]

  k_cast_x<<<dim3(4096), dim3(256), 0, stream>>>(x, xbf, 1048576);
  k_transpose_w<<<dim3(16, 48), dim3(256), 0, stream>>>(Wqkv, wqT, 1024, 3072);
  k_transpose_w<<<dim3(16, 16), dim3(256), 0, stream>>>(Wo, woT, 1024, 1024);
  k_gemm<0><<<dim3(32, 24), dim3(256), 0, stream>>>(xbf, wqT, bqkv, Qb, Kb, Vt, nullptr);
  k_attn<<<dim3(512), dim3(256), 0, stream>>>(Qb, Kb, Vt, attn, ctx);
  k_gemm<1><<<dim3(32, 8), dim3(256), 0, stream>>>(ctx, woT, bo, nullptr, nullptr, nullptr, out);
}

// Round 15
// 232.852 us; speedup vs baseline: 1.3243x; 1.0318x over previous
//
#include <hip/hip_runtime.h>
#include <stdint.h>

typedef __attribute__((ext_vector_type(8))) short bf16x8;
typedef __attribute__((ext_vector_type(4))) float f32x4;
typedef __attribute__((ext_vector_type(4))) unsigned int u32x4;
typedef __attribute__((ext_vector_type(4))) unsigned short u16x4;

#define DEVINL static __device__ __forceinline__

DEVINL unsigned short f2bf(float f) {
  uint32_t u = __builtin_bit_cast(uint32_t, f);
  u = (u + 0x7FFFu + ((u >> 16) & 1u)) >> 16;
  return (unsigned short)u;
}

DEVINL float fexp2(float x) {
#if __has_builtin(__builtin_amdgcn_exp2f)
  return __builtin_amdgcn_exp2f(x);
#else
  return __expf(x * 0.69314718056f);
#endif
}

DEVINL void raw_barrier() {
  __builtin_amdgcn_sched_barrier(0);
  __builtin_amdgcn_s_barrier();
  __builtin_amdgcn_sched_barrier(0);
}

// barrier B: order LDS ops, then block barrier (stores stay in flight)
DEVINL void barrier_lds_only() {
  asm volatile("s_waitcnt lgkmcnt(0)" ::: "memory");
  raw_barrier();
}

// pack 8 fp32 -> 8 bf16 (RNE) via v_cvt_pk_bf16_f32 (register-only asm)
DEVINL bf16x8 pack8(f32x4 a, f32x4 b) {
  union { uint32_t u[4]; bf16x8 v; } r;
  asm("v_cvt_pk_bf16_f32 %0, %1, %2" : "=v"(r.u[0]) : "v"(a[0]), "v"(a[1]));
  asm("v_cvt_pk_bf16_f32 %0, %1, %2" : "=v"(r.u[1]) : "v"(a[2]), "v"(a[3]));
  asm("v_cvt_pk_bf16_f32 %0, %1, %2" : "=v"(r.u[2]) : "v"(b[0]), "v"(b[1]));
  asm("v_cvt_pk_bf16_f32 %0, %1, %2" : "=v"(r.u[3]) : "v"(b[2]), "v"(b[3]));
  return r.v;
}

// async global->LDS, 16B per lane; lds base must be wave-uniform (lane*16 implicit)
DEVINL void async16(const unsigned short* lds, const unsigned short* g) {
  __builtin_amdgcn_global_load_lds(
      (const __attribute__((address_space(1))) unsigned int*)g,
      (__attribute__((address_space(3))) unsigned int*)lds, 16, 0, 0);
}

// ---------------- fused prep: cast x + transpose Wqkv + transpose Wo ----------------
// bid < 4096: cast x chunk; bid in [4096,4864): Wqkv transpose; else Wo transpose.
__global__ __launch_bounds__(256) void k_prep(const float* __restrict__ x,
                                              unsigned short* __restrict__ xbf,
                                              const float* __restrict__ Wqkv,
                                              unsigned short* __restrict__ wqT,
                                              const float* __restrict__ Wo,
                                              unsigned short* __restrict__ woT) {
  int bid = blockIdx.x;
  int t = threadIdx.x;
  if (bid < 4096) {
    int i = bid * 256 + t;
    f32x4 v = *(const f32x4*)(x + (size_t)i * 4);
    u16x4 o;
    for (int j = 0; j < 4; ++j) o[j] = f2bf(v[j]);
    *(u16x4*)(xbf + (size_t)i * 4) = o;
    return;
  }
  __shared__ unsigned short tile[64][72];
  const float* in;
  unsigned short* out;
  int K = 1024, N, k0, n0;
  if (bid < 4864) {
    int b = bid - 4096;             // 0..767 ; orig dim3(16,48): x=b%16, y=b/16
    N = 3072; k0 = (b & 15) * 64; n0 = (b >> 4) * 64;
    in = Wqkv; out = wqT;
  } else {
    int b = bid - 4864;             // 0..255 ; orig dim3(16,16)
    N = 1024; k0 = (b & 15) * 64; n0 = (b >> 4) * 64;
    in = Wo; out = woT;
  }
  int r = t >> 2, c0 = (t & 3) * 16;
  for (int j = 0; j < 4; ++j) {
    int col = c0 + j * 4;
    f32x4 v = *(const f32x4*)(in + (size_t)(k0 + r) * N + n0 + col);
    u16x4 o;
    for (int q = 0; q < 4; ++q) o[q] = f2bf(v[q]);
    *(u16x4*)(&tile[r][col]) = o;
  }
  __syncthreads();
  for (int j = 0; j < 4; ++j) {
    int kcol = c0 + j * 4;
    u16x4 o;
    for (int q = 0; q < 4; ++q) o[q] = tile[kcol + q][r];
    *(u16x4*)(out + (size_t)(n0 + r) * K + k0 + kcol) = o;
  }
}

// ---------------- GEMM: A[M][1024] bf16  x  Bt[N][1024] bf16 ----------------
template <int MODE>
__global__ __launch_bounds__(256) void k_gemm(const unsigned short* __restrict__ A,
                                              const unsigned short* __restrict__ Bt,
                                              const float* __restrict__ bias,
                                              unsigned short* __restrict__ Qb,
                                              unsigned short* __restrict__ Kb,
                                              unsigned short* __restrict__ Vt,
                                              float* __restrict__ outF) {
  constexpr int KD = 1024;
  __shared__ unsigned short sh[17408];
  unsigned short* lA = sh;
  unsigned short* lB = sh + 8192;
  int tid = threadIdx.x;
  int lane = tid & 63, w = tid >> 6;
  int wr = w >> 1, wc = w & 1;
  int m0 = blockIdx.x * 128, n0 = blockIdx.y * 128;
  int lr = lane & 15, lg = lane >> 4;

  f32x4 acc[4][4] = {};

  int srow = w * 32 + (lane >> 3);
  int scol = (lane & 7) * 8;
  const unsigned short* gA = A + (size_t)(m0 + srow) * KD + scol;
  const unsigned short* gB = Bt + (size_t)(n0 + srow) * KD + scol;

  for (int kk = 0; kk < KD; kk += 64) {
    for (int s = 0; s < 4; ++s) {
      async16(&lA[(w * 32 + s * 8) * 64], gA + (size_t)s * 8 * KD + kk);
      async16(&lB[(w * 32 + s * 8) * 64], gB + (size_t)s * 8 * KD + kk);
    }
    __syncthreads();
    for (int kq = 0; kq < 2; ++kq) {
      bf16x8 af[4], bfr[4];
      for (int i = 0; i < 4; ++i)
        af[i] = *(const bf16x8*)(&lA[(wr * 64 + i * 16 + lr) * 64 + (kq * 4 + lg) * 8]);
      for (int r = 0; r < 4; ++r)
        bfr[r] = *(const bf16x8*)(&lB[(wc * 64 + r * 16 + lr) * 64 + (kq * 4 + lg) * 8]);
      for (int i = 0; i < 4; ++i)
        for (int r = 0; r < 4; ++r)
          acc[i][r] = __builtin_amdgcn_mfma_f32_16x16x32_bf16(af[i], bfr[r], acc[i][r], 0, 0, 0);
    }
    __syncthreads();
  }

  if (MODE == 0) {
    int which = n0 >> 10;
    int head0 = (n0 & 1023) >> 6;
    int b_idx = m0 >> 11;
    int l0 = m0 & 2047;
    if (which < 2) {
      for (int r = 0; r < 4; ++r) {
        int nl = wc * 64 + r * 16 + lr;
        float bv = bias[n0 + nl];
        for (int i = 0; i < 4; ++i) {
          int mlb = wr * 64 + i * 16 + lg * 4;
          for (int jj = 0; jj < 4; ++jj)
            sh[(mlb + jj) * 136 + nl] = f2bf(acc[i][r][jj] + bv);
        }
      }
      __syncthreads();
      unsigned short* dst = (which == 0) ? Qb : Kb;
      for (int it = 0; it < 4; ++it) {
        int row = it * 64 + (tid >> 2);
        int ml = row & 127, hd = row >> 7;
        int c = (tid & 3) * 16;
        bf16x8 v0 = *(const bf16x8*)&sh[ml * 136 + hd * 64 + c];
        bf16x8 v1 = *(const bf16x8*)&sh[ml * 136 + hd * 64 + c + 8];
        size_t bh = (size_t)(b_idx * 16 + head0 + hd);
        size_t off = (bh * 2048 + l0 + ml) * 64 + c;
        *(bf16x8*)(dst + off) = v0;
        *(bf16x8*)(dst + off + 8) = v1;
      }
    } else {
      for (int r = 0; r < 4; ++r) {
        int nl = wc * 64 + r * 16 + lr;
        float bv = bias[n0 + nl];
        for (int i = 0; i < 4; ++i) {
          int mlb = wr * 64 + i * 16 + lg * 4;
          u16x4 pk;
          for (int jj = 0; jj < 4; ++jj) pk[jj] = f2bf(acc[i][r][jj] + bv);
          *(u16x4*)&sh[nl * 136 + mlb] = pk;
        }
      }
      __syncthreads();
      for (int it = 0; it < 4; ++it) {
        int nl = it * 32 + (tid >> 3);
        int c = (tid & 7) * 16;
        bf16x8 v0 = *(const bf16x8*)&sh[nl * 136 + c];
        bf16x8 v1 = *(const bf16x8*)&sh[nl * 136 + c + 8];
        int dk = nl & 63, hd = nl >> 6;
        size_t bh = (size_t)(b_idx * 16 + head0 + hd);
        size_t off = (bh * 64 + dk) * 2048 + l0 + c;
        *(bf16x8*)(Vt + off) = v0;
        *(bf16x8*)(Vt + off + 8) = v1;
      }
    }
  } else {
    for (int r = 0; r < 4; ++r) {
      int n = n0 + wc * 64 + r * 16 + lr;
      float bv = bias[n];
      for (int i = 0; i < 4; ++i) {
        int mb = m0 + wr * 64 + i * 16 + lg * 4;
        for (int jj = 0; jj < 4; ++jj)
          outF[(size_t)(mb + jj) * 1024 + n] = acc[i][r][jj] + bv;
      }
    }
  }
}

// ---------------- fused attention (v7: swapped QK^T -> vectorized P writes) ----------------
// R14 structure (staged LDS K/V, double-buffer, counted vmcnt) with the QK^T
// operands SWAPPED: acc = mfma(kf, qf). Lane then holds 4 CONSECUTIVE keys for
// one q-row (q = i*16+lr, keys = r*16+lg*4+{0..3}), so the P-tile write is
// 8x ds_write_b128 instead of 32x ds_write_b32, and the row-sum reduce is
// 2 shfls (xor 16,32) instead of 4. All other paths byte-identical to R14.
__global__ __launch_bounds__(256) void k_attn(const unsigned short* __restrict__ Qb,
                                              const unsigned short* __restrict__ Kb,
                                              const unsigned short* __restrict__ Vt,
                                              float* __restrict__ attn,
                                              unsigned short* __restrict__ ctx) {
  __shared__ unsigned short Ks[2][4096];   // 16 KB: [key][d], chunk-XOR swizzled
  __shared__ unsigned short Vs[2][4096];   // 16 KB: [dk][key], chunk-XOR swizzled
  __shared__ float Pf[4][32 * 68];         // ~35 KB per-wave P tiles
  int tid = threadIdx.x, lane = tid & 63, w = tid >> 6;
  int lr = lane & 15, lg = lane >> 4;
  int bid = blockIdx.x;
  int xcd = bid & 7, slot = bid >> 3;
  int bh = xcd * 4 + (slot >> 4);          // 4 heads per XCD -> K/V L2-resident
  int qb = slot & 15;
  int q0 = qb * 128 + w * 32;
  int b_idx = bh >> 4, h = bh & 15;
  const unsigned short* Qh = Qb + (size_t)bh * 2048 * 64;
  const unsigned short* Kh = Kb + (size_t)bh * 2048 * 64;
  const unsigned short* Vh = Vt + (size_t)bh * 64 * 2048;
  float* Pw = &Pf[w][0];
  const float A2 = 0.125f * 1.44269504089f;  // scale * log2(e)
  int e7 = lr & 7;                            // read-side swizzle key (row&7 == lr&7)

  // staging source pointers (pre-swizzled chunk; both-sides involution)
  int srow = w * 8 + (lane >> 3);            // rows 0..31 (call 0), +32 (call 1)
  int sc = (lane & 7) ^ (srow & 7);          // (srow+32)&7 == srow&7, same sc
  const unsigned short* gK = Kh + (size_t)srow * 64 + sc * 8;
  const unsigned short* gV = Vh + (size_t)srow * 2048 + sc * 8;

  bf16x8 qf[2][2];
  for (int i = 0; i < 2; ++i)
    for (int kq = 0; kq < 2; ++kq)
      qf[i][kq] = *(const bf16x8*)(Qh + (size_t)(q0 + i * 16 + lr) * 64 + kq * 32 + lg * 8);

  float l_run[2] = {0.f, 0.f};

  // ---- pass 1: K double-buffered, counted vmcnt; swapped mfma(K, Q) ----
  async16(&Ks[0][(w * 8) * 64],       gK);
  async16(&Ks[0][((w + 4) * 8) * 64], gK + 2048);
  for (int kt = 0; kt < 32; ++kt) {
    int cur = kt & 1;
    if (kt < 31) {
      async16(&Ks[cur ^ 1][(w * 8) * 64],       gK + (size_t)(kt + 1) * 4096);
      async16(&Ks[cur ^ 1][((w + 4) * 8) * 64], gK + (size_t)(kt + 1) * 4096 + 2048);
      asm volatile("s_waitcnt vmcnt(2)" ::: "memory");
    } else {
      asm volatile("s_waitcnt vmcnt(0)" ::: "memory");
    }
    raw_barrier();                          // barrier A: current K tile ready
    f32x4 acc[2][4] = {};
    for (int kq = 0; kq < 2; ++kq) {
      int j = kq * 4 + lg;
      bf16x8 kf[4];
      for (int r = 0; r < 4; ++r)
        kf[r] = *(const bf16x8*)&Ks[cur][(r * 16 + lr) * 64 + ((j ^ e7) << 3)];
      for (int i = 0; i < 2; ++i)
        for (int r = 0; r < 4; ++r)
          acc[i][r] = __builtin_amdgcn_mfma_f32_16x16x32_bf16(kf[r], qf[i][kq], acc[i][r], 0, 0, 0);
    }
    for (int i = 0; i < 2; ++i)
      for (int r = 0; r < 4; ++r)
        l_run[i] += fexp2(acc[i][r][0] * A2) + fexp2(acc[i][r][1] * A2) +
                    fexp2(acc[i][r][2] * A2) + fexp2(acc[i][r][3] * A2);
    barrier_lds_only();                     // barrier B: reads done before overwrite
  }
  float invl[2];
  for (int i = 0; i < 2; ++i) {
    float s = l_run[i];
    s += __shfl_xor(s, 16);
    s += __shfl_xor(s, 32);
    invl[i] = 1.0f / s;
  }

  // ---- pass 2: K+V double-buffered, counted vmcnt; stores never drained in-loop ----
  f32x4 cacc[2][4] = {};
  float* attn_base = attn + (size_t)bh * 2048 * 2048;
  float* arow = attn_base + (size_t)(q0 + lg) * 2048 + lr * 4;

  async16(&Ks[0][(w * 8) * 64],       gK);
  async16(&Ks[0][((w + 4) * 8) * 64], gK + 2048);
  async16(&Vs[0][(w * 8) * 64],       gV);
  async16(&Vs[0][((w + 4) * 8) * 64], gV + 65536);
  for (int kt = 0; kt < 32; ++kt) {
    int cur = kt & 1;
    if (kt < 31) {
      async16(&Ks[cur ^ 1][(w * 8) * 64],       gK + (size_t)(kt + 1) * 4096);
      async16(&Ks[cur ^ 1][((w + 4) * 8) * 64], gK + (size_t)(kt + 1) * 4096 + 2048);
      async16(&Vs[cur ^ 1][(w * 8) * 64],       gV + (size_t)(kt + 1) * 64);
      async16(&Vs[cur ^ 1][((w + 4) * 8) * 64], gV + (size_t)(kt + 1) * 64 + 65536);
    }
    if (kt == 0)       asm volatile("s_waitcnt vmcnt(4)" ::: "memory");
    else if (kt == 31) asm volatile("s_waitcnt vmcnt(8)" ::: "memory");
    else               asm volatile("s_waitcnt vmcnt(12)" ::: "memory");
    raw_barrier();                          // barrier A: current K/V tiles ready
    f32x4 acc[2][4] = {};
    for (int kq = 0; kq < 2; ++kq) {
      int j = kq * 4 + lg;
      bf16x8 kf[4];
      for (int r = 0; r < 4; ++r)
        kf[r] = *(const bf16x8*)&Ks[cur][(r * 16 + lr) * 64 + ((j ^ e7) << 3)];
      for (int i = 0; i < 2; ++i)
        for (int r = 0; r < 4; ++r)
          acc[i][r] = __builtin_amdgcn_mfma_f32_16x16x32_bf16(kf[r], qf[i][kq], acc[i][r], 0, 0, 0);
    }
    // p -> per-wave fp32 LDS tile: lane holds q=i*16+lr, keys r*16+lg*4+{0..3}
    // -> one ds_write_b128 per (i,r)
    for (int i = 0; i < 2; ++i)
      for (int r = 0; r < 4; ++r) {
        f32x4 pv;
        for (int jj = 0; jj < 4; ++jj)
          pv[jj] = fexp2(acc[i][r][jj] * A2) * invl[i];
        *(f32x4*)&Pw[(i * 16 + lr) * 68 + r * 16 + lg * 4] = pv;
      }
    // coalesced attn write: 8 x f32x4 per lane, 256B contiguous per row
    for (int s = 0; s < 8; ++s) {
      f32x4 v = *(const f32x4*)(&Pw[(s * 4 + lg) * 68 + lr * 4]);
      __builtin_nontemporal_store(v, (f32x4*)(arow + (size_t)s * 4 * 2048 + kt * 64));
    }
    // PV: A = P (fp32 tile -> cvt_pk bf16), B = V from LDS
    for (int kq2 = 0; kq2 < 2; ++kq2) {
      int j = kq2 * 4 + lg;
      int kof = kq2 * 32 + lg * 8;
      bf16x8 pa[2], vf[4];
      for (int i = 0; i < 2; ++i) {
        f32x4 plo = *(const f32x4*)(&Pw[(i * 16 + lr) * 68 + kof]);
        f32x4 phi = *(const f32x4*)(&Pw[(i * 16 + lr) * 68 + kof + 4]);
        pa[i] = pack8(plo, phi);
      }
      for (int nn = 0; nn < 4; ++nn)
        vf[nn] = *(const bf16x8*)&Vs[cur][(nn * 16 + lr) * 64 + ((j ^ e7) << 3)];
      for (int i = 0; i < 2; ++i)
        for (int nn = 0; nn < 4; ++nn)
          cacc[i][nn] = __builtin_amdgcn_mfma_f32_16x16x32_bf16(pa[i], vf[nn], cacc[i][nn], 0, 0, 0);
    }
    barrier_lds_only();                     // barrier B: reads done before overwrite
  }

  for (int nn = 0; nn < 4; ++nn) {
    int d = nn * 16 + lr;
    for (int i = 0; i < 2; ++i)
      for (int jj = 0; jj < 4; ++jj) {
        int q = q0 + i * 16 + lg * 4 + jj;
        int tok = b_idx * 2048 + q;
        ctx[(size_t)tok * 1024 + h * 64 + d] = f2bf(cacc[i][nn][jj]);
      }
  }
}

extern "C" void kernel_launch(void* const* d_in, const int* in_sizes, int n_in,
                              void* d_out, int out_size, void* d_ws, size_t ws_size,
                              hipStream_t stream) {
  const float* x    = (const float*)d_in[0];
  const float* Wqkv = (const float*)d_in[1];
  const float* bqkv = (const float*)d_in[2];
  const float* Wo   = (const float*)d_in[3];
  const float* bo   = (const float*)d_in[4];
  float* out  = (float*)d_out;
  float* attn = out + (size_t)4096 * 1024;

  char* ws = (char*)d_ws;
  unsigned short* xbf = (unsigned short*)(ws);              //  8 MB  [4096][1024]
  unsigned short* wqT = (unsigned short*)(ws + 8388608);    //  6 MB  [3072][1024]
  unsigned short* woT = (unsigned short*)(ws + 14680064);   //  2 MB  [1024][1024]
  unsigned short* Qb  = (unsigned short*)(ws + 16777216);   //  8 MB  [32][2048][64]
  unsigned short* Kb  = (unsigned short*)(ws + 25165824);   //  8 MB  [32][2048][64]
  unsigned short* Vt  = (unsigned short*)(ws + 33554432);   //  8 MB  [32][64][2048]
  unsigned short* ctx = (unsigned short*)(ws + 41943040);   //  8 MB  [4096][1024]

  k_prep<<<dim3(5120), dim3(256), 0, stream>>>(x, xbf, Wqkv, wqT, Wo, woT);
  k_gemm<0><<<dim3(32, 24), dim3(256), 0, stream>>>(xbf, wqT, bqkv, Qb, Kb, Vt, nullptr);
  k_attn<<<dim3(512), dim3(256), 0, stream>>>(Qb, Kb, Vt, attn, ctx);
  k_gemm<1><<<dim3(32, 8), dim3(256), 0, stream>>>(ctx, woT, bo, nullptr, nullptr, nullptr, out);
}

// Round 16
// 222.726 us; speedup vs baseline: 1.3845x; 1.0455x over previous
//
#include <hip/hip_runtime.h>
#include <stdint.h>

typedef __attribute__((ext_vector_type(8))) short bf16x8;
typedef __attribute__((ext_vector_type(4))) float f32x4;
typedef __attribute__((ext_vector_type(4))) unsigned int u32x4;
typedef __attribute__((ext_vector_type(2))) unsigned int u32x2;
typedef __attribute__((ext_vector_type(4))) unsigned short u16x4;

#define DEVINL static __device__ __forceinline__

DEVINL unsigned short f2bf(float f) {
  uint32_t u = __builtin_bit_cast(uint32_t, f);
  u = (u + 0x7FFFu + ((u >> 16) & 1u)) >> 16;
  return (unsigned short)u;
}

DEVINL float fexp2(float x) {
#if __has_builtin(__builtin_amdgcn_exp2f)
  return __builtin_amdgcn_exp2f(x);
#else
  return __expf(x * 0.69314718056f);
#endif
}

DEVINL void raw_barrier() {
  __builtin_amdgcn_sched_barrier(0);
  __builtin_amdgcn_s_barrier();
  __builtin_amdgcn_sched_barrier(0);
}

// barrier B: order LDS ops, then block barrier (stores stay in flight)
DEVINL void barrier_lds_only() {
  asm volatile("s_waitcnt lgkmcnt(0)" ::: "memory");
  raw_barrier();
}

// async global->LDS, 16B per lane; lds base must be wave-uniform (lane*16 implicit)
DEVINL void async16(const unsigned short* lds, const unsigned short* g) {
  __builtin_amdgcn_global_load_lds(
      (const __attribute__((address_space(1))) unsigned int*)g,
      (__attribute__((address_space(3))) unsigned int*)lds, 16, 0, 0);
}

// ---------------- fused prep: cast x + transpose Wqkv + transpose Wo ----------------
__global__ __launch_bounds__(256) void k_prep(const float* __restrict__ x,
                                              unsigned short* __restrict__ xbf,
                                              const float* __restrict__ Wqkv,
                                              unsigned short* __restrict__ wqT,
                                              const float* __restrict__ Wo,
                                              unsigned short* __restrict__ woT) {
  int bid = blockIdx.x;
  int t = threadIdx.x;
  if (bid < 4096) {
    int i = bid * 256 + t;
    f32x4 v = *(const f32x4*)(x + (size_t)i * 4);
    u16x4 o;
    for (int j = 0; j < 4; ++j) o[j] = f2bf(v[j]);
    *(u16x4*)(xbf + (size_t)i * 4) = o;
    return;
  }
  __shared__ unsigned short tile[64][72];
  const float* in;
  unsigned short* out;
  int K = 1024, N, k0, n0;
  if (bid < 4864) {
    int b = bid - 4096;
    N = 3072; k0 = (b & 15) * 64; n0 = (b >> 4) * 64;
    in = Wqkv; out = wqT;
  } else {
    int b = bid - 4864;
    N = 1024; k0 = (b & 15) * 64; n0 = (b >> 4) * 64;
    in = Wo; out = woT;
  }
  int r = t >> 2, c0 = (t & 3) * 16;
  for (int j = 0; j < 4; ++j) {
    int col = c0 + j * 4;
    f32x4 v = *(const f32x4*)(in + (size_t)(k0 + r) * N + n0 + col);
    u16x4 o;
    for (int q = 0; q < 4; ++q) o[q] = f2bf(v[q]);
    *(u16x4*)(&tile[r][col]) = o;
  }
  __syncthreads();
  for (int j = 0; j < 4; ++j) {
    int kcol = c0 + j * 4;
    u16x4 o;
    for (int q = 0; q < 4; ++q) o[q] = tile[kcol + q][r];
    *(u16x4*)(out + (size_t)(n0 + r) * K + k0 + kcol) = o;
  }
}

// ---------------- GEMM: A[M][1024] bf16  x  Bt[N][1024] bf16 ----------------
template <int MODE>
__global__ __launch_bounds__(256) void k_gemm(const unsigned short* __restrict__ A,
                                              const unsigned short* __restrict__ Bt,
                                              const float* __restrict__ bias,
                                              unsigned short* __restrict__ Qb,
                                              unsigned short* __restrict__ Kb,
                                              unsigned short* __restrict__ Vt,
                                              float* __restrict__ outF) {
  constexpr int KD = 1024;
  __shared__ unsigned short sh[17408];
  unsigned short* lA = sh;
  unsigned short* lB = sh + 8192;
  int tid = threadIdx.x;
  int lane = tid & 63, w = tid >> 6;
  int wr = w >> 1, wc = w & 1;
  int m0 = blockIdx.x * 128, n0 = blockIdx.y * 128;
  int lr = lane & 15, lg = lane >> 4;

  f32x4 acc[4][4] = {};

  int srow = w * 32 + (lane >> 3);
  int scol = (lane & 7) * 8;
  const unsigned short* gA = A + (size_t)(m0 + srow) * KD + scol;
  const unsigned short* gB = Bt + (size_t)(n0 + srow) * KD + scol;

  for (int kk = 0; kk < KD; kk += 64) {
    for (int s = 0; s < 4; ++s) {
      async16(&lA[(w * 32 + s * 8) * 64], gA + (size_t)s * 8 * KD + kk);
      async16(&lB[(w * 32 + s * 8) * 64], gB + (size_t)s * 8 * KD + kk);
    }
    __syncthreads();
    for (int kq = 0; kq < 2; ++kq) {
      bf16x8 af[4], bfr[4];
      for (int i = 0; i < 4; ++i)
        af[i] = *(const bf16x8*)(&lA[(wr * 64 + i * 16 + lr) * 64 + (kq * 4 + lg) * 8]);
      for (int r = 0; r < 4; ++r)
        bfr[r] = *(const bf16x8*)(&lB[(wc * 64 + r * 16 + lr) * 64 + (kq * 4 + lg) * 8]);
      for (int i = 0; i < 4; ++i)
        for (int r = 0; r < 4; ++r)
          acc[i][r] = __builtin_amdgcn_mfma_f32_16x16x32_bf16(af[i], bfr[r], acc[i][r], 0, 0, 0);
    }
    __syncthreads();
  }

  if (MODE == 0) {
    int which = n0 >> 10;
    int head0 = (n0 & 1023) >> 6;
    int b_idx = m0 >> 11;
    int l0 = m0 & 2047;
    if (which < 2) {
      for (int r = 0; r < 4; ++r) {
        int nl = wc * 64 + r * 16 + lr;
        float bv = bias[n0 + nl];
        for (int i = 0; i < 4; ++i) {
          int mlb = wr * 64 + i * 16 + lg * 4;
          for (int jj = 0; jj < 4; ++jj)
            sh[(mlb + jj) * 136 + nl] = f2bf(acc[i][r][jj] + bv);
        }
      }
      __syncthreads();
      unsigned short* dst = (which == 0) ? Qb : Kb;
      for (int it = 0; it < 4; ++it) {
        int row = it * 64 + (tid >> 2);
        int ml = row & 127, hd = row >> 7;
        int c = (tid & 3) * 16;
        bf16x8 v0 = *(const bf16x8*)&sh[ml * 136 + hd * 64 + c];
        bf16x8 v1 = *(const bf16x8*)&sh[ml * 136 + hd * 64 + c + 8];
        size_t bh = (size_t)(b_idx * 16 + head0 + hd);
        size_t off = (bh * 2048 + l0 + ml) * 64 + c;
        *(bf16x8*)(dst + off) = v0;
        *(bf16x8*)(dst + off + 8) = v1;
      }
    } else {
      for (int r = 0; r < 4; ++r) {
        int nl = wc * 64 + r * 16 + lr;
        float bv = bias[n0 + nl];
        for (int i = 0; i < 4; ++i) {
          int mlb = wr * 64 + i * 16 + lg * 4;
          u16x4 pk;
          for (int jj = 0; jj < 4; ++jj) pk[jj] = f2bf(acc[i][r][jj] + bv);
          *(u16x4*)&sh[nl * 136 + mlb] = pk;
        }
      }
      __syncthreads();
      for (int it = 0; it < 4; ++it) {
        int nl = it * 32 + (tid >> 3);
        int c = (tid & 7) * 16;
        bf16x8 v0 = *(const bf16x8*)&sh[nl * 136 + c];
        bf16x8 v1 = *(const bf16x8*)&sh[nl * 136 + c + 8];
        int dk = nl & 63, hd = nl >> 6;
        size_t bh = (size_t)(b_idx * 16 + head0 + hd);
        size_t off = (bh * 64 + dk) * 2048 + l0 + c;
        *(bf16x8*)(Vt + off) = v0;
        *(bf16x8*)(Vt + off + 8) = v1;
      }
    }
  } else {
    for (int r = 0; r < 4; ++r) {
      int n = n0 + wc * 64 + r * 16 + lr;
      float bv = bias[n];
      for (int i = 0; i < 4; ++i) {
        int mb = m0 + wr * 64 + i * 16 + lg * 4;
        for (int jj = 0; jj < 4; ++jj)
          outF[(size_t)(mb + jj) * 1024 + n] = acc[i][r][jj] + bv;
      }
    }
  }
}

// ---------------- fused attention (v8: bf16 P-tile + quad-buffered pass 1) ----------------
// R15 structure with: (1) P staged as packed bf16 pairs (stride 36 u32) -- PV
// path reads same bf16 values as R15's pack8 (ctx bit-identical); attn output
// is bf16(p) (+~3e-6 abs). Halves P-tile LDS traffic, deletes pack8.
// (2) pass 1 quad-buffers K across KVs[4] (Vs unused in pass 1): stage kt+2,
// wait vmcnt(4), ONE barrier per kt (buffer reuse 2 barriers away).
__global__ __launch_bounds__(256) void k_attn(const unsigned short* __restrict__ Qb,
                                              const unsigned short* __restrict__ Kb,
                                              const unsigned short* __restrict__ Vt,
                                              float* __restrict__ attn,
                                              unsigned short* __restrict__ ctx) {
  __shared__ unsigned short KVs[4][4096];  // 32 KB: p1: 4x K-buf; p2: K=KVs[0/1], V=KVs[2/3]
  __shared__ uint32_t Pb[4][32 * 36];      // 18 KB: packed bf16 P, per-wave
  int tid = threadIdx.x, lane = tid & 63, w = tid >> 6;
  int lr = lane & 15, lg = lane >> 4;
  int bid = blockIdx.x;
  int xcd = bid & 7, slot = bid >> 3;
  int bh = xcd * 4 + (slot >> 4);          // 4 heads per XCD -> K/V L2-resident
  int qb = slot & 15;
  int q0 = qb * 128 + w * 32;
  int b_idx = bh >> 4, h = bh & 15;
  const unsigned short* Qh = Qb + (size_t)bh * 2048 * 64;
  const unsigned short* Kh = Kb + (size_t)bh * 2048 * 64;
  const unsigned short* Vh = Vt + (size_t)bh * 64 * 2048;
  uint32_t* PwB = &Pb[w][0];
  const float A2 = 0.125f * 1.44269504089f;  // scale * log2(e)
  int e7 = lr & 7;                            // read-side swizzle key (row&7 == lr&7)

  // staging source pointers (pre-swizzled chunk; both-sides involution)
  int srow = w * 8 + (lane >> 3);
  int sc = (lane & 7) ^ (srow & 7);
  const unsigned short* gK = Kh + (size_t)srow * 64 + sc * 8;
  const unsigned short* gV = Vh + (size_t)srow * 2048 + sc * 8;

  bf16x8 qf[2][2];
  for (int i = 0; i < 2; ++i)
    for (int kq = 0; kq < 2; ++kq)
      qf[i][kq] = *(const bf16x8*)(Qh + (size_t)(q0 + i * 16 + lr) * 64 + kq * 32 + lg * 8);

  float l_run[2] = {0.f, 0.f};

  // ---- pass 1: quad-buffered K, single barrier per kt; swapped mfma(K, Q) ----
  async16(&KVs[0][(w * 8) * 64],       gK);
  async16(&KVs[0][((w + 4) * 8) * 64], gK + 2048);
  async16(&KVs[1][(w * 8) * 64],       gK + 4096);
  async16(&KVs[1][((w + 4) * 8) * 64], gK + 4096 + 2048);
  for (int kt = 0; kt < 32; ++kt) {
    const unsigned short* Kc = KVs[kt & 3];
    if (kt < 30) {
      async16(&KVs[(kt + 2) & 3][(w * 8) * 64],       gK + (size_t)(kt + 2) * 4096);
      async16(&KVs[(kt + 2) & 3][((w + 4) * 8) * 64], gK + (size_t)(kt + 2) * 4096 + 2048);
      asm volatile("s_waitcnt vmcnt(4)" ::: "memory");
    } else if (kt == 30) {
      asm volatile("s_waitcnt vmcnt(2)" ::: "memory");
    } else {
      asm volatile("s_waitcnt vmcnt(0)" ::: "memory");
    }
    raw_barrier();                          // single barrier: tile kt ready; reuse is 2 barriers away
    f32x4 acc[2][4] = {};
    for (int kq = 0; kq < 2; ++kq) {
      int j = kq * 4 + lg;
      bf16x8 kf[4];
      for (int r = 0; r < 4; ++r)
        kf[r] = *(const bf16x8*)&Kc[(r * 16 + lr) * 64 + ((j ^ e7) << 3)];
      for (int i = 0; i < 2; ++i)
        for (int r = 0; r < 4; ++r)
          acc[i][r] = __builtin_amdgcn_mfma_f32_16x16x32_bf16(kf[r], qf[i][kq], acc[i][r], 0, 0, 0);
    }
    for (int i = 0; i < 2; ++i)
      for (int r = 0; r < 4; ++r)
        l_run[i] += fexp2(acc[i][r][0] * A2) + fexp2(acc[i][r][1] * A2) +
                    fexp2(acc[i][r][2] * A2) + fexp2(acc[i][r][3] * A2);
  }
  float invl[2];
  for (int i = 0; i < 2; ++i) {
    float s = l_run[i];
    s += __shfl_xor(s, 16);
    s += __shfl_xor(s, 32);
    invl[i] = 1.0f / s;
  }

  // ---- pass 2: K+V double-buffered, counted vmcnt; bf16 P tile ----
  f32x4 cacc[2][4] = {};
  float* attn_base = attn + (size_t)bh * 2048 * 2048;
  float* arow = attn_base + (size_t)(q0 + lg) * 2048 + lr * 4;

  barrier_lds_only();                       // pass-1 reads done before pass-2 staging
  async16(&KVs[0][(w * 8) * 64],       gK);
  async16(&KVs[0][((w + 4) * 8) * 64], gK + 2048);
  async16(&KVs[2][(w * 8) * 64],       gV);
  async16(&KVs[2][((w + 4) * 8) * 64], gV + 65536);
  for (int kt = 0; kt < 32; ++kt) {
    int cur = kt & 1;
    if (kt < 31) {
      async16(&KVs[cur ^ 1][(w * 8) * 64],       gK + (size_t)(kt + 1) * 4096);
      async16(&KVs[cur ^ 1][((w + 4) * 8) * 64], gK + (size_t)(kt + 1) * 4096 + 2048);
      async16(&KVs[2 + (cur ^ 1)][(w * 8) * 64],       gV + (size_t)(kt + 1) * 64);
      async16(&KVs[2 + (cur ^ 1)][((w + 4) * 8) * 64], gV + (size_t)(kt + 1) * 64 + 65536);
    }
    if (kt == 0)       asm volatile("s_waitcnt vmcnt(4)" ::: "memory");
    else if (kt == 31) asm volatile("s_waitcnt vmcnt(8)" ::: "memory");
    else               asm volatile("s_waitcnt vmcnt(12)" ::: "memory");
    raw_barrier();                          // barrier A: current K/V tiles ready
    const unsigned short* Kc = KVs[cur];
    const unsigned short* Vc = KVs[2 + cur];
    f32x4 acc[2][4] = {};
    for (int kq = 0; kq < 2; ++kq) {
      int j = kq * 4 + lg;
      bf16x8 kf[4];
      for (int r = 0; r < 4; ++r)
        kf[r] = *(const bf16x8*)&Kc[(r * 16 + lr) * 64 + ((j ^ e7) << 3)];
      for (int i = 0; i < 2; ++i)
        for (int r = 0; r < 4; ++r)
          acc[i][r] = __builtin_amdgcn_mfma_f32_16x16x32_bf16(kf[r], qf[i][kq], acc[i][r], 0, 0, 0);
    }
    // p -> packed bf16 LDS tile: lane holds q=i*16+lr, keys r*16+lg*4+{0..3}
    for (int i = 0; i < 2; ++i)
      for (int r = 0; r < 4; ++r) {
        float p0 = fexp2(acc[i][r][0] * A2) * invl[i];
        float p1 = fexp2(acc[i][r][1] * A2) * invl[i];
        float p2 = fexp2(acc[i][r][2] * A2) * invl[i];
        float p3 = fexp2(acc[i][r][3] * A2) * invl[i];
        uint32_t u0, u1;
        asm("v_cvt_pk_bf16_f32 %0, %1, %2" : "=v"(u0) : "v"(p0), "v"(p1));
        asm("v_cvt_pk_bf16_f32 %0, %1, %2" : "=v"(u1) : "v"(p2), "v"(p3));
        u32x2 uu; uu[0] = u0; uu[1] = u1;
        *(u32x2*)&PwB[(i * 16 + lr) * 36 + r * 8 + lg * 2] = uu;
      }
    // coalesced attn write: 8 rows/lane-group, unpack bf16 -> f32x4, 1KB contiguous
    for (int s = 0; s < 8; ++s) {
      int row = s * 4 + lg;
      u32x2 d = *(const u32x2*)&PwB[row * 36 + lr * 2];
      f32x4 v;
      v[0] = __builtin_bit_cast(float, d[0] << 16);
      v[1] = __builtin_bit_cast(float, d[0] & 0xFFFF0000u);
      v[2] = __builtin_bit_cast(float, d[1] << 16);
      v[3] = __builtin_bit_cast(float, d[1] & 0xFFFF0000u);
      __builtin_nontemporal_store(v, (f32x4*)(arow + (size_t)s * 4 * 2048 + kt * 64));
    }
    // PV: A = P (direct bf16x8 from tile), B = V from LDS
    for (int kq2 = 0; kq2 < 2; ++kq2) {
      int j = kq2 * 4 + lg;
      bf16x8 pa[2], vf[4];
      for (int i = 0; i < 2; ++i)
        pa[i] = *(const bf16x8*)&PwB[(i * 16 + lr) * 36 + kq2 * 16 + lg * 4];
      for (int nn = 0; nn < 4; ++nn)
        vf[nn] = *(const bf16x8*)&Vc[(nn * 16 + lr) * 64 + ((j ^ e7) << 3)];
      for (int i = 0; i < 2; ++i)
        for (int nn = 0; nn < 4; ++nn)
          cacc[i][nn] = __builtin_amdgcn_mfma_f32_16x16x32_bf16(pa[i], vf[nn], cacc[i][nn], 0, 0, 0);
    }
    barrier_lds_only();                     // barrier B: reads done before overwrite
  }

  for (int nn = 0; nn < 4; ++nn) {
    int d = nn * 16 + lr;
    for (int i = 0; i < 2; ++i)
      for (int jj = 0; jj < 4; ++jj) {
        int q = q0 + i * 16 + lg * 4 + jj;
        int tok = b_idx * 2048 + q;
        ctx[(size_t)tok * 1024 + h * 64 + d] = f2bf(cacc[i][nn][jj]);
      }
  }
}

extern "C" void kernel_launch(void* const* d_in, const int* in_sizes, int n_in,
                              void* d_out, int out_size, void* d_ws, size_t ws_size,
                              hipStream_t stream) {
  const float* x    = (const float*)d_in[0];
  const float* Wqkv = (const float*)d_in[1];
  const float* bqkv = (const float*)d_in[2];
  const float* Wo   = (const float*)d_in[3];
  const float* bo   = (const float*)d_in[4];
  float* out  = (float*)d_out;
  float* attn = out + (size_t)4096 * 1024;

  char* ws = (char*)d_ws;
  unsigned short* xbf = (unsigned short*)(ws);              //  8 MB  [4096][1024]
  unsigned short* wqT = (unsigned short*)(ws + 8388608);    //  6 MB  [3072][1024]
  unsigned short* woT = (unsigned short*)(ws + 14680064);   //  2 MB  [1024][1024]
  unsigned short* Qb  = (unsigned short*)(ws + 16777216);   //  8 MB  [32][2048][64]
  unsigned short* Kb  = (unsigned short*)(ws + 25165824);   //  8 MB  [32][2048][64]
  unsigned short* Vt  = (unsigned short*)(ws + 33554432);   //  8 MB  [32][64][2048]
  unsigned short* ctx = (unsigned short*)(ws + 41943040);   //  8 MB  [4096][1024]

  k_prep<<<dim3(5120), dim3(256), 0, stream>>>(x, xbf, Wqkv, wqT, Wo, woT);
  k_gemm<0><<<dim3(32, 24), dim3(256), 0, stream>>>(xbf, wqT, bqkv, Qb, Kb, Vt, nullptr);
  k_attn<<<dim3(512), dim3(256), 0, stream>>>(Qb, Kb, Vt, attn, ctx);
  k_gemm<1><<<dim3(32, 8), dim3(256), 0, stream>>>(ctx, woT, bo, nullptr, nullptr, nullptr, out);
}

// Round 17
// 217.049 us; speedup vs baseline: 1.4207x; 1.0262x over previous
//
#include <hip/hip_runtime.h>
#include <stdint.h>

typedef __attribute__((ext_vector_type(8))) short bf16x8;
typedef __attribute__((ext_vector_type(4))) float f32x4;
typedef __attribute__((ext_vector_type(4))) unsigned int u32x4;
typedef __attribute__((ext_vector_type(2))) unsigned int u32x2;
typedef __attribute__((ext_vector_type(4))) unsigned short u16x4;

#define DEVINL static __device__ __forceinline__

DEVINL unsigned short f2bf(float f) {
  uint32_t u = __builtin_bit_cast(uint32_t, f);
  u = (u + 0x7FFFu + ((u >> 16) & 1u)) >> 16;
  return (unsigned short)u;
}

DEVINL float fexp2(float x) {
#if __has_builtin(__builtin_amdgcn_exp2f)
  return __builtin_amdgcn_exp2f(x);
#else
  return __expf(x * 0.69314718056f);
#endif
}

DEVINL void raw_barrier() {
  __builtin_amdgcn_sched_barrier(0);
  __builtin_amdgcn_s_barrier();
  __builtin_amdgcn_sched_barrier(0);
}

// async global->LDS, 16B per lane; lds base must be wave-uniform (lane*16 implicit)
DEVINL void async16(const unsigned short* lds, const unsigned short* g) {
  __builtin_amdgcn_global_load_lds(
      (const __attribute__((address_space(1))) unsigned int*)g,
      (__attribute__((address_space(3))) unsigned int*)lds, 16, 0, 0);
}

// ---------------- fused prep: cast x + transpose Wqkv + transpose Wo ----------------
__global__ __launch_bounds__(256) void k_prep(const float* __restrict__ x,
                                              unsigned short* __restrict__ xbf,
                                              const float* __restrict__ Wqkv,
                                              unsigned short* __restrict__ wqT,
                                              const float* __restrict__ Wo,
                                              unsigned short* __restrict__ woT) {
  int bid = blockIdx.x;
  int t = threadIdx.x;
  if (bid < 4096) {
    int i = bid * 256 + t;
    f32x4 v = *(const f32x4*)(x + (size_t)i * 4);
    u16x4 o;
    for (int j = 0; j < 4; ++j) o[j] = f2bf(v[j]);
    *(u16x4*)(xbf + (size_t)i * 4) = o;
    return;
  }
  __shared__ unsigned short tile[64][72];
  const float* in;
  unsigned short* out;
  int K = 1024, N, k0, n0;
  if (bid < 4864) {
    int b = bid - 4096;
    N = 3072; k0 = (b & 15) * 64; n0 = (b >> 4) * 64;
    in = Wqkv; out = wqT;
  } else {
    int b = bid - 4864;
    N = 1024; k0 = (b & 15) * 64; n0 = (b >> 4) * 64;
    in = Wo; out = woT;
  }
  int r = t >> 2, c0 = (t & 3) * 16;
  for (int j = 0; j < 4; ++j) {
    int col = c0 + j * 4;
    f32x4 v = *(const f32x4*)(in + (size_t)(k0 + r) * N + n0 + col);
    u16x4 o;
    for (int q = 0; q < 4; ++q) o[q] = f2bf(v[q]);
    *(u16x4*)(&tile[r][col]) = o;
  }
  __syncthreads();
  for (int j = 0; j < 4; ++j) {
    int kcol = c0 + j * 4;
    u16x4 o;
    for (int q = 0; q < 4; ++q) o[q] = tile[kcol + q][r];
    *(u16x4*)(out + (size_t)(n0 + r) * K + k0 + kcol) = o;
  }
}

// ---------------- GEMM: A[M][1024] bf16  x  Bt[N][1024] bf16 ----------------
template <int MODE>
__global__ __launch_bounds__(256) void k_gemm(const unsigned short* __restrict__ A,
                                              const unsigned short* __restrict__ Bt,
                                              const float* __restrict__ bias,
                                              unsigned short* __restrict__ Qb,
                                              unsigned short* __restrict__ Kb,
                                              unsigned short* __restrict__ Vt,
                                              float* __restrict__ outF) {
  constexpr int KD = 1024;
  __shared__ unsigned short sh[17408];
  unsigned short* lA = sh;
  unsigned short* lB = sh + 8192;
  int tid = threadIdx.x;
  int lane = tid & 63, w = tid >> 6;
  int wr = w >> 1, wc = w & 1;
  int m0 = blockIdx.x * 128, n0 = blockIdx.y * 128;
  int lr = lane & 15, lg = lane >> 4;

  f32x4 acc[4][4] = {};

  int srow = w * 32 + (lane >> 3);
  int scol = (lane & 7) * 8;
  const unsigned short* gA = A + (size_t)(m0 + srow) * KD + scol;
  const unsigned short* gB = Bt + (size_t)(n0 + srow) * KD + scol;

  for (int kk = 0; kk < KD; kk += 64) {
    for (int s = 0; s < 4; ++s) {
      async16(&lA[(w * 32 + s * 8) * 64], gA + (size_t)s * 8 * KD + kk);
      async16(&lB[(w * 32 + s * 8) * 64], gB + (size_t)s * 8 * KD + kk);
    }
    __syncthreads();
    for (int kq = 0; kq < 2; ++kq) {
      bf16x8 af[4], bfr[4];
      for (int i = 0; i < 4; ++i)
        af[i] = *(const bf16x8*)(&lA[(wr * 64 + i * 16 + lr) * 64 + (kq * 4 + lg) * 8]);
      for (int r = 0; r < 4; ++r)
        bfr[r] = *(const bf16x8*)(&lB[(wc * 64 + r * 16 + lr) * 64 + (kq * 4 + lg) * 8]);
      for (int i = 0; i < 4; ++i)
        for (int r = 0; r < 4; ++r)
          acc[i][r] = __builtin_amdgcn_mfma_f32_16x16x32_bf16(af[i], bfr[r], acc[i][r], 0, 0, 0);
    }
    __syncthreads();
  }

  if (MODE == 0) {
    int which = n0 >> 10;
    int head0 = (n0 & 1023) >> 6;
    int b_idx = m0 >> 11;
    int l0 = m0 & 2047;
    if (which < 2) {
      for (int r = 0; r < 4; ++r) {
        int nl = wc * 64 + r * 16 + lr;
        float bv = bias[n0 + nl];
        for (int i = 0; i < 4; ++i) {
          int mlb = wr * 64 + i * 16 + lg * 4;
          for (int jj = 0; jj < 4; ++jj)
            sh[(mlb + jj) * 136 + nl] = f2bf(acc[i][r][jj] + bv);
        }
      }
      __syncthreads();
      unsigned short* dst = (which == 0) ? Qb : Kb;
      for (int it = 0; it < 4; ++it) {
        int row = it * 64 + (tid >> 2);
        int ml = row & 127, hd = row >> 7;
        int c = (tid & 3) * 16;
        bf16x8 v0 = *(const bf16x8*)&sh[ml * 136 + hd * 64 + c];
        bf16x8 v1 = *(const bf16x8*)&sh[ml * 136 + hd * 64 + c + 8];
        size_t bh = (size_t)(b_idx * 16 + head0 + hd);
        size_t off = (bh * 2048 + l0 + ml) * 64 + c;
        *(bf16x8*)(dst + off) = v0;
        *(bf16x8*)(dst + off + 8) = v1;
      }
    } else {
      for (int r = 0; r < 4; ++r) {
        int nl = wc * 64 + r * 16 + lr;
        float bv = bias[n0 + nl];
        for (int i = 0; i < 4; ++i) {
          int mlb = wr * 64 + i * 16 + lg * 4;
          u16x4 pk;
          for (int jj = 0; jj < 4; ++jj) pk[jj] = f2bf(acc[i][r][jj] + bv);
          *(u16x4*)&sh[nl * 136 + mlb] = pk;
        }
      }
      __syncthreads();
      for (int it = 0; it < 4; ++it) {
        int nl = it * 32 + (tid >> 3);
        int c = (tid & 7) * 16;
        bf16x8 v0 = *(const bf16x8*)&sh[nl * 136 + c];
        bf16x8 v1 = *(const bf16x8*)&sh[nl * 136 + c + 8];
        int dk = nl & 63, hd = nl >> 6;
        size_t bh = (size_t)(b_idx * 16 + head0 + hd);
        size_t off = (bh * 64 + dk) * 2048 + l0 + c;
        *(bf16x8*)(Vt + off) = v0;
        *(bf16x8*)(Vt + off + 8) = v1;
      }
    }
  } else {
    for (int r = 0; r < 4; ++r) {
      int n = n0 + wc * 64 + r * 16 + lr;
      float bv = bias[n];
      for (int i = 0; i < 4; ++i) {
        int mb = m0 + wr * 64 + i * 16 + lg * 4;
        for (int jj = 0; jj < 4; ++jj)
          outF[(size_t)(mb + jj) * 1024 + n] = acc[i][r][jj] + bv;
      }
    }
  }
}

// ---------------- fused attention (v9: merged barriers + setprio) ----------------
// R16 math bit-identical. Pass 1: 2 tiles per barrier (16 barriers), stage
// issued AFTER the barrier (reuse distance 2 barriers). Pass 2: 1 barrier per
// kt: vmcnt(8)+lgkmcnt(0) -> barrier -> stage(kt+1) -> compute; stores stay
// in flight. setprio(1) around MFMA clusters (T5).
__global__ __launch_bounds__(256) void k_attn(const unsigned short* __restrict__ Qb,
                                              const unsigned short* __restrict__ Kb,
                                              const unsigned short* __restrict__ Vt,
                                              float* __restrict__ attn,
                                              unsigned short* __restrict__ ctx) {
  __shared__ unsigned short KVs[4][4096];  // 32 KB
  __shared__ uint32_t Pb[4][32 * 36];      // 18 KB: packed bf16 P, per-wave
  int tid = threadIdx.x, lane = tid & 63, w = tid >> 6;
  int lr = lane & 15, lg = lane >> 4;
  int bid = blockIdx.x;
  int xcd = bid & 7, slot = bid >> 3;
  int bh = xcd * 4 + (slot >> 4);
  int qb = slot & 15;
  int q0 = qb * 128 + w * 32;
  int b_idx = bh >> 4, h = bh & 15;
  const unsigned short* Qh = Qb + (size_t)bh * 2048 * 64;
  const unsigned short* Kh = Kb + (size_t)bh * 2048 * 64;
  const unsigned short* Vh = Vt + (size_t)bh * 64 * 2048;
  uint32_t* PwB = &Pb[w][0];
  const float A2 = 0.125f * 1.44269504089f;
  int e7 = lr & 7;

  int srow = w * 8 + (lane >> 3);
  int sc = (lane & 7) ^ (srow & 7);
  const unsigned short* gK = Kh + (size_t)srow * 64 + sc * 8;
  const unsigned short* gV = Vh + (size_t)srow * 2048 + sc * 8;

  bf16x8 qf[2][2];
  for (int i = 0; i < 2; ++i)
    for (int kq = 0; kq < 2; ++kq)
      qf[i][kq] = *(const bf16x8*)(Qh + (size_t)(q0 + i * 16 + lr) * 64 + kq * 32 + lg * 8);

  float l_run[2] = {0.f, 0.f};

  // ---- pass 1: 2 tiles per barrier, quad-buffered ----
  async16(&KVs[0][(w * 8) * 64],       gK);
  async16(&KVs[0][((w + 4) * 8) * 64], gK + 2048);
  async16(&KVs[1][(w * 8) * 64],       gK + 4096);
  async16(&KVs[1][((w + 4) * 8) * 64], gK + 4096 + 2048);
  for (int j = 0; j < 16; ++j) {
    asm volatile("s_waitcnt vmcnt(0) lgkmcnt(0)" ::: "memory");
    raw_barrier();
    if (j < 15) {
      int t2 = 2 * j + 2, t3 = 2 * j + 3;
      async16(&KVs[t2 & 3][(w * 8) * 64],       gK + (size_t)t2 * 4096);
      async16(&KVs[t2 & 3][((w + 4) * 8) * 64], gK + (size_t)t2 * 4096 + 2048);
      async16(&KVs[t3 & 3][(w * 8) * 64],       gK + (size_t)t3 * 4096);
      async16(&KVs[t3 & 3][((w + 4) * 8) * 64], gK + (size_t)t3 * 4096 + 2048);
    }
    for (int u = 0; u < 2; ++u) {
      int kt = 2 * j + u;
      const unsigned short* Kc = KVs[kt & 3];
      f32x4 acc[2][4] = {};
      bf16x8 kf[2][4];
      for (int kq = 0; kq < 2; ++kq) {
        int jx = kq * 4 + lg;
        for (int r = 0; r < 4; ++r)
          kf[kq][r] = *(const bf16x8*)&Kc[(r * 16 + lr) * 64 + ((jx ^ e7) << 3)];
      }
      __builtin_amdgcn_s_setprio(1);
      for (int kq = 0; kq < 2; ++kq)
        for (int i = 0; i < 2; ++i)
          for (int r = 0; r < 4; ++r)
            acc[i][r] = __builtin_amdgcn_mfma_f32_16x16x32_bf16(kf[kq][r], qf[i][kq], acc[i][r], 0, 0, 0);
      __builtin_amdgcn_s_setprio(0);
      for (int i = 0; i < 2; ++i)
        for (int r = 0; r < 4; ++r)
          l_run[i] += fexp2(acc[i][r][0] * A2) + fexp2(acc[i][r][1] * A2) +
                      fexp2(acc[i][r][2] * A2) + fexp2(acc[i][r][3] * A2);
    }
  }
  float invl[2];
  for (int i = 0; i < 2; ++i) {
    float s = l_run[i];
    s += __shfl_xor(s, 16);
    s += __shfl_xor(s, 32);
    invl[i] = 1.0f / s;
  }

  // ---- pass 2: single barrier per kt; stores stay in flight ----
  f32x4 cacc[2][4] = {};
  float* attn_base = attn + (size_t)bh * 2048 * 2048;
  float* arow = attn_base + (size_t)(q0 + lg) * 2048 + lr * 4;

  asm volatile("s_waitcnt lgkmcnt(0)" ::: "memory");
  raw_barrier();                            // pass-1 reads done before pass-2 staging
  async16(&KVs[0][(w * 8) * 64],       gK);
  async16(&KVs[0][((w + 4) * 8) * 64], gK + 2048);
  async16(&KVs[2][(w * 8) * 64],       gV);
  async16(&KVs[2][((w + 4) * 8) * 64], gV + 65536);
  for (int kt = 0; kt < 32; ++kt) {
    int cur = kt & 1;
    if (kt == 0) asm volatile("s_waitcnt vmcnt(0) lgkmcnt(0)" ::: "memory");
    else         asm volatile("s_waitcnt vmcnt(8) lgkmcnt(0)" ::: "memory");
    raw_barrier();
    if (kt < 31) {
      async16(&KVs[cur ^ 1][(w * 8) * 64],       gK + (size_t)(kt + 1) * 4096);
      async16(&KVs[cur ^ 1][((w + 4) * 8) * 64], gK + (size_t)(kt + 1) * 4096 + 2048);
      async16(&KVs[2 + (cur ^ 1)][(w * 8) * 64],       gV + (size_t)(kt + 1) * 64);
      async16(&KVs[2 + (cur ^ 1)][((w + 4) * 8) * 64], gV + (size_t)(kt + 1) * 64 + 65536);
    }
    const unsigned short* Kc = KVs[cur];
    const unsigned short* Vc = KVs[2 + cur];
    f32x4 acc[2][4] = {};
    bf16x8 kf[2][4];
    for (int kq = 0; kq < 2; ++kq) {
      int jx = kq * 4 + lg;
      for (int r = 0; r < 4; ++r)
        kf[kq][r] = *(const bf16x8*)&Kc[(r * 16 + lr) * 64 + ((jx ^ e7) << 3)];
    }
    __builtin_amdgcn_s_setprio(1);
    for (int kq = 0; kq < 2; ++kq)
      for (int i = 0; i < 2; ++i)
        for (int r = 0; r < 4; ++r)
          acc[i][r] = __builtin_amdgcn_mfma_f32_16x16x32_bf16(kf[kq][r], qf[i][kq], acc[i][r], 0, 0, 0);
    __builtin_amdgcn_s_setprio(0);
    // p -> packed bf16 LDS tile
    for (int i = 0; i < 2; ++i)
      for (int r = 0; r < 4; ++r) {
        float p0 = fexp2(acc[i][r][0] * A2) * invl[i];
        float p1 = fexp2(acc[i][r][1] * A2) * invl[i];
        float p2 = fexp2(acc[i][r][2] * A2) * invl[i];
        float p3 = fexp2(acc[i][r][3] * A2) * invl[i];
        uint32_t u0, u1;
        asm("v_cvt_pk_bf16_f32 %0, %1, %2" : "=v"(u0) : "v"(p0), "v"(p1));
        asm("v_cvt_pk_bf16_f32 %0, %1, %2" : "=v"(u1) : "v"(p2), "v"(p3));
        u32x2 uu; uu[0] = u0; uu[1] = u1;
        *(u32x2*)&PwB[(i * 16 + lr) * 36 + r * 8 + lg * 2] = uu;
      }
    // PV first (MFMA issues early); store phase after (fire-and-forget)
    for (int kq2 = 0; kq2 < 2; ++kq2) {
      int jx = kq2 * 4 + lg;
      bf16x8 pa[2], vf[4];
      for (int i = 0; i < 2; ++i)
        pa[i] = *(const bf16x8*)&PwB[(i * 16 + lr) * 36 + kq2 * 16 + lg * 4];
      for (int nn = 0; nn < 4; ++nn)
        vf[nn] = *(const bf16x8*)&Vc[(nn * 16 + lr) * 64 + ((jx ^ e7) << 3)];
      __builtin_amdgcn_s_setprio(1);
      for (int i = 0; i < 2; ++i)
        for (int nn = 0; nn < 4; ++nn)
          cacc[i][nn] = __builtin_amdgcn_mfma_f32_16x16x32_bf16(pa[i], vf[nn], cacc[i][nn], 0, 0, 0);
      __builtin_amdgcn_s_setprio(0);
    }
    // coalesced attn write: 8 rows/lane-group, unpack bf16 -> f32x4, 1KB contiguous
    for (int s = 0; s < 8; ++s) {
      int row = s * 4 + lg;
      u32x2 d = *(const u32x2*)&PwB[row * 36 + lr * 2];
      f32x4 v;
      v[0] = __builtin_bit_cast(float, d[0] << 16);
      v[1] = __builtin_bit_cast(float, d[0] & 0xFFFF0000u);
      v[2] = __builtin_bit_cast(float, d[1] << 16);
      v[3] = __builtin_bit_cast(float, d[1] & 0xFFFF0000u);
      __builtin_nontemporal_store(v, (f32x4*)(arow + (size_t)s * 4 * 2048 + kt * 64));
    }
  }

  for (int nn = 0; nn < 4; ++nn) {
    int d = nn * 16 + lr;
    for (int i = 0; i < 2; ++i)
      for (int jj = 0; jj < 4; ++jj) {
        int q = q0 + i * 16 + lg * 4 + jj;
        int tok = b_idx * 2048 + q;
        ctx[(size_t)tok * 1024 + h * 64 + d] = f2bf(cacc[i][nn][jj]);
      }
  }
}

extern "C" void kernel_launch(void* const* d_in, const int* in_sizes, int n_in,
                              void* d_out, int out_size, void* d_ws, size_t ws_size,
                              hipStream_t stream) {
  const float* x    = (const float*)d_in[0];
  const float* Wqkv = (const float*)d_in[1];
  const float* bqkv = (const float*)d_in[2];
  const float* Wo   = (const float*)d_in[3];
  const float* bo   = (const float*)d_in[4];
  float* out  = (float*)d_out;
  float* attn = out + (size_t)4096 * 1024;

  char* ws = (char*)d_ws;
  unsigned short* xbf = (unsigned short*)(ws);              //  8 MB  [4096][1024]
  unsigned short* wqT = (unsigned short*)(ws + 8388608);    //  6 MB  [3072][1024]
  unsigned short* woT = (unsigned short*)(ws + 14680064);   //  2 MB  [1024][1024]
  unsigned short* Qb  = (unsigned short*)(ws + 16777216);   //  8 MB  [32][2048][64]
  unsigned short* Kb  = (unsigned short*)(ws + 25165824);   //  8 MB  [32][2048][64]
  unsigned short* Vt  = (unsigned short*)(ws + 33554432);   //  8 MB  [32][64][2048]
  unsigned short* ctx = (unsigned short*)(ws + 41943040);   //  8 MB  [4096][1024]

  k_prep<<<dim3(5120), dim3(256), 0, stream>>>(x, xbf, Wqkv, wqT, Wo, woT);
  k_gemm<0><<<dim3(32, 24), dim3(256), 0, stream>>>(xbf, wqT, bqkv, Qb, Kb, Vt, nullptr);
  k_attn<<<dim3(512), dim3(256), 0, stream>>>(Qb, Kb, Vt, attn, ctx);
  k_gemm<1><<<dim3(32, 8), dim3(256), 0, stream>>>(ctx, woT, bo, nullptr, nullptr, nullptr, out);
}